// Round 1
// baseline (341.529 us; speedup 1.0000x reference)
//
#include <hip/hip_runtime.h>

typedef unsigned short u16;
typedef short bf16x8 __attribute__((ext_vector_type(8)));
typedef float f32x4 __attribute__((ext_vector_type(4)));
typedef unsigned short u16x4 __attribute__((ext_vector_type(4)));

#define AS1 __attribute__((address_space(1)))
#define AS3 __attribute__((address_space(3)))

__device__ __forceinline__ u16 f2bf(float f) {
    unsigned u = __float_as_uint(f);
    u += 0x7fff + ((u >> 16) & 1);   // round-to-nearest-even
    return (u16)(u >> 16);
}

__device__ __forceinline__ void gld16(const void* g, void* l) {
    __builtin_amdgcn_global_load_lds((const AS1 void*)g, (AS3 void*)l, 16, 0, 0);
}

// ---------------- fused fp32 -> bf16 conversion for x, Wq, Wk, Wv, Wo ----------------
__global__ void convall_kernel(const float* __restrict__ x,  const float* __restrict__ wq,
                               const float* __restrict__ wk, const float* __restrict__ wv,
                               const float* __restrict__ wo,
                               u16* __restrict__ xb, u16* __restrict__ wqkv, u16* __restrict__ wob) {
    int t = blockIdx.x * 256 + threadIdx.x;
    const float* srcs[5] = { x, wq, wk, wv, wo };
    u16* dsts[5] = { xb, wqkv, wqkv + 4194304, wqkv + 8388608, wob };
#pragma unroll
    for (int r = 0; r < 5; r++) {
        f32x4 v = ((const f32x4*)srcs[r])[t];
        u16x4 o = { f2bf(v.x), f2bf(v.y), f2bf(v.z), f2bf(v.w) };
        ((u16x4*)dsts[r])[t] = o;
    }
}

// ---------------- cache_k: copy fp32 -> d_out K region + bf16 convert ----------------
__global__ void cachek_kernel(const float* __restrict__ ck, float* __restrict__ kout,
                              u16* __restrict__ kcb) {
    const int n4 = (2 * 16 * 1024 * 128) / 4;   // 1048576
    int i = blockIdx.x * 256 + threadIdx.x;
    int stride = gridDim.x * 256;
    for (; i < n4; i += stride) {
        f32x4 v = ((const f32x4*)ck)[i];
        int bh = i >> 15;
        ((f32x4*)kout)[i + bh * 32768] = v;      // [bh,s<1024,d] -> [bh*2048+s,d]
        u16x4 o = { f2bf(v.x), f2bf(v.y), f2bf(v.z), f2bf(v.w) };
        ((u16x4*)kcb)[i] = o;
    }
}

// ---------------- cache_v: copy fp32 -> d_out V region + bf16 transpose [bh,d,s] ----------------
__global__ void vtrans_kernel(const float* __restrict__ cv, float* __restrict__ vout,
                              u16* __restrict__ vtb) {
    __shared__ u16 tile[64 * 65];
    const int bh = blockIdx.x;
    const int s0 = blockIdx.y * 64;
    const int d0 = blockIdx.z * 64;
    const float* src = cv + (size_t)bh * 1024 * 128;
#pragma unroll
    for (int i = 0; i < 16; i++) {
        int e = i * 256 + threadIdx.x;
        int sr = e >> 6, dc = e & 63;
        float v = src[(size_t)(s0 + sr) * 128 + d0 + dc];
        vout[((size_t)bh * 2048 + s0 + sr) * 128 + d0 + dc] = v;
        tile[sr * 65 + dc] = f2bf(v);
    }
    __syncthreads();
    u16* dst = vtb + (size_t)bh * 128 * 1024;
#pragma unroll
    for (int i = 0; i < 16; i++) {
        int e = i * 256 + threadIdx.x;
        int dr = e >> 6, sc = e & 63;
        dst[(size_t)(d0 + dr) * 1024 + s0 + sc] = tile[sc * 65 + dr];
    }
}

// ---------------- QKV GEMM: 128x128 tile, 4 waves (2x2 of 64x64), BK=64 ----------------
// m97 structure (measured ~900 TF at 3 blocks/CU): 32 MFMA per wave per K-step,
// XOR-swizzled LDS, global_load_lds width-16 staging. Grid 48x16 = 768 = 3 blocks/CU.
// Epilogue scatters Q (bf16, pre-scaled), K/V (fp32 into cache slots 1024..2047).
__global__ __launch_bounds__(256) void gemm_qkv_kernel(
    const u16* __restrict__ A, const u16* __restrict__ Bm,
    u16* __restrict__ qout, float* __restrict__ kout, float* __restrict__ vout) {
    __shared__ u16 As[128 * 64];    // 16 KB
    __shared__ u16 Bs[128 * 64];    // 16 KB
    const int tid = threadIdx.x;
    const int lane = tid & 63, wv = tid >> 6;
    const int wr = (wv >> 1) * 64;       // wave row offset within tile
    const int wc = (wv & 1) * 64;        // wave col offset within tile
    const int m0 = blockIdx.y * 128, n0 = blockIdx.x * 128;
    const int frow = lane & 15, fq = lane >> 4;
    const int swz = frow & 7;

    f32x4 acc[4][4];
#pragma unroll
    for (int a = 0; a < 4; a++)
#pragma unroll
        for (int b = 0; b < 4; b++) acc[a][b] = (f32x4){0.f, 0.f, 0.f, 0.f};

    for (int k0 = 0; k0 < 2048; k0 += 64) {
        __syncthreads();
#pragma unroll
        for (int i = 0; i < 4; i++) {
            int L = i * 256 + tid;             // A chunks 0..1023 (128 rows x 8)
            int row = L >> 3;
            int c = (L & 7) ^ (row & 7);
            gld16(A + (size_t)(m0 + row) * 2048 + k0 + c * 8, As + i * 2048 + wv * 512);
        }
#pragma unroll
        for (int i = 0; i < 4; i++) {
            int L = i * 256 + tid;             // B chunks 0..1023
            int row = L >> 3;
            int c = (L & 7) ^ (row & 7);
            gld16(Bm + (size_t)(n0 + row) * 2048 + k0 + c * 8, Bs + i * 2048 + wv * 512);
        }
        __syncthreads();
#pragma unroll
        for (int kk = 0; kk < 2; kk++) {
            bf16x8 aF[4], bF[4];
#pragma unroll
            for (int f = 0; f < 4; f++)
                aF[f] = *(const bf16x8*)(As + (wr + f * 16 + frow) * 64 + ((kk * 4 + fq) ^ swz) * 8);
#pragma unroll
            for (int f = 0; f < 4; f++)
                bF[f] = *(const bf16x8*)(Bs + (wc + f * 16 + frow) * 64 + ((kk * 4 + fq) ^ swz) * 8);
#pragma unroll
            for (int fm = 0; fm < 4; fm++)
#pragma unroll
                for (int fn = 0; fn < 4; fn++)
                    acc[fm][fn] = __builtin_amdgcn_mfma_f32_16x16x32_bf16(aF[fm], bF[fn], acc[fm][fn], 0, 0, 0);
        }
    }

#pragma unroll
    for (int fm = 0; fm < 4; fm++) {
#pragma unroll
        for (int fn = 0; fn < 4; fn++) {
#pragma unroll
            for (int r = 0; r < 4; r++) {
                int m = m0 + wr + fm * 16 + fq * 4 + r;
                int n = n0 + wc + fn * 16 + frow;
                float v = acc[fm][fn][r];
                int b = m >> 10, t = m & 1023;
                int sect = n >> 11, nn = n & 2047;
                int h = nn >> 7, d = nn & 127;
                size_t bh = (size_t)(b * 16 + h);
                if (sect == 0)
                    qout[(bh * 1024 + t) * 128 + d] = f2bf(v * 0.08838834764831843f);
                else if (sect == 1)
                    kout[(bh * 2048 + 1024 + t) * 128 + d] = v;
                else
                    vout[(bh * 2048 + 1024 + t) * 128 + d] = v;
            }
        }
    }
}

// ---------------- out-proj GEMM: C[m,n] = sum_k A[m,k]*B[n,k], K=2048 ----------------
// 64x128 tile, 4 waves (each 64x32), BK=64, XOR-swizzled LDS (24 KB).
// Kept at 64x128: grid 16x32 = 512 blocks = 2/CU; 128^2 would drop to 1/CU (m102: ~320 TF).
__global__ __launch_bounds__(256) void gemm_out_kernel(
    const u16* __restrict__ A, const u16* __restrict__ Bm, float* __restrict__ cout) {
    __shared__ u16 As[64 * 64];     // 8 KB
    __shared__ u16 Bs[128 * 64];    // 16 KB
    const int tid = threadIdx.x;
    const int lane = tid & 63, wv = tid >> 6;
    const int wn = wv * 32;
    const int m0 = blockIdx.y * 64, n0 = blockIdx.x * 128;
    const int frow = lane & 15, fq = lane >> 4;
    const int swz = frow & 7;

    f32x4 acc[4][2];
#pragma unroll
    for (int a = 0; a < 4; a++)
#pragma unroll
        for (int b = 0; b < 2; b++) acc[a][b] = (f32x4){0.f, 0.f, 0.f, 0.f};

    for (int k0 = 0; k0 < 2048; k0 += 64) {
        __syncthreads();
#pragma unroll
        for (int i = 0; i < 2; i++) {
            int L = i * 256 + tid;             // A chunk 0..511
            int row = L >> 3;
            int c = (L & 7) ^ (row & 7);
            gld16(A + (size_t)(m0 + row) * 2048 + k0 + c * 8, As + i * 2048 + wv * 512);
        }
#pragma unroll
        for (int i = 0; i < 4; i++) {
            int L = i * 256 + tid;             // B chunk 0..1023
            int row = L >> 3;
            int c = (L & 7) ^ (row & 7);
            gld16(Bm + (size_t)(n0 + row) * 2048 + k0 + c * 8, Bs + i * 2048 + wv * 512);
        }
        __syncthreads();
#pragma unroll
        for (int kk = 0; kk < 2; kk++) {
            bf16x8 aF[4], bF[2];
#pragma unroll
            for (int f = 0; f < 4; f++)
                aF[f] = *(const bf16x8*)(As + (f * 16 + frow) * 64 + ((kk * 4 + fq) ^ swz) * 8);
#pragma unroll
            for (int f = 0; f < 2; f++)
                bF[f] = *(const bf16x8*)(Bs + (wn + f * 16 + frow) * 64 + ((kk * 4 + fq) ^ swz) * 8);
#pragma unroll
            for (int fm = 0; fm < 4; fm++)
#pragma unroll
                for (int fn = 0; fn < 2; fn++)
                    acc[fm][fn] = __builtin_amdgcn_mfma_f32_16x16x32_bf16(aF[fm], bF[fn], acc[fm][fn], 0, 0, 0);
        }
    }

#pragma unroll
    for (int fm = 0; fm < 4; fm++) {
#pragma unroll
        for (int fn = 0; fn < 2; fn++) {
#pragma unroll
            for (int r = 0; r < 4; r++) {
                int m = m0 + fm * 16 + fq * 4 + r;
                int n = n0 + wn + fn * 16 + frow;
                cout[(size_t)m * 2048 + n] = acc[fm][fn][r];
            }
        }
    }
}

// ---------------- flash attention, s-split for load balance ----------------
// 768 blocks, heavy-first:
//  bid<512: partial chunks of qi in [8,15]: qi = 15-(bid>>6), bh=(bid&63)>>1, c=bid&1.
//           chunk0 = tiles [0,ceil(n/2)), chunk1 = rest (incl. diagonal). Writes raw
//           m/l/O partials to workspace (overlaid on dead Wqkv region).
//  bid>=512: full blocks qi in [0,7] (loads 1..8), qi = 7-((bid-512)>>5), bh=(bid-512)&31.
// All block loads in [1..8.5] tiles; 768 blocks on 512 slots -> LPT-style balance.
__global__ __launch_bounds__(256) void attn_kernel(
    const u16* __restrict__ Qb, const u16* __restrict__ Kcb,
    const u16* __restrict__ Vtb, u16* __restrict__ AOb,
    float* __restrict__ PO, float* __restrict__ PML) {
    __shared__ u16 Qs[64 * 128];   // [t_local][d]  swizzled
    __shared__ u16 Ks[64 * 128];   // [s_local][d]  swizzled
    __shared__ u16 Vs[128 * 64];   // [d][s_local]  swizzled
    __shared__ u16 Ps[64 * 64];    // [t_local][s_local] swizzled
    const int bid = blockIdx.x;
    int bh, qi, st_begin, st_end, cidx;
    bool partial;
    if (bid < 512) {
        qi = 15 - (bid >> 6);
        int j = bid & 63;
        bh = j >> 1;
        int c = j & 1;
        int n = qi + 1, h0 = (n + 1) >> 1;
        st_begin = c ? h0 : 0;
        st_end = c ? n : h0;
        partial = true;
        cidx = c * 256 + bh * 8 + (qi - 8);
    } else {
        int j = bid - 512;
        qi = 7 - (j >> 5);
        bh = j & 31;
        st_begin = 0; st_end = qi + 1;
        partial = false; cidx = 0;
    }
    const int t0 = qi * 64;
    const int tid = threadIdx.x, lane = tid & 63, wv = tid >> 6;
    const int row_w = wv * 16;
    const int frow = lane & 15, fq = lane >> 4;
    const int swz = frow & 7;

    // stage Q (64x128 = 1024 chunks)
    const u16* Qg = Qb + ((size_t)bh * 1024 + t0) * 128;
#pragma unroll
    for (int i = 0; i < 4; i++) {
        int L = i * 256 + tid;
        int row = L >> 4;
        int c = (L & 15) ^ (row & 7);
        gld16(Qg + row * 128 + c * 8, Qs + i * 2048 + wv * 512);
    }

    float mrow[4], lrow[4];
    f32x4 Oacc[8];
#pragma unroll
    for (int r = 0; r < 4; r++) { mrow[r] = -1e30f; lrow[r] = 0.f; }
#pragma unroll
    for (int fd = 0; fd < 8; fd++) Oacc[fd] = (f32x4){0.f, 0.f, 0.f, 0.f};

    for (int st = st_begin; st < st_end; st++) {
        int s0 = st * 64;
        __syncthreads();
        const u16* Kg = Kcb + ((size_t)bh * 1024 + s0) * 128;
#pragma unroll
        for (int i = 0; i < 4; i++) {
            int L = i * 256 + tid;
            int row = L >> 4;
            int c = (L & 15) ^ (row & 7);
            gld16(Kg + row * 128 + c * 8, Ks + i * 2048 + wv * 512);
        }
        const u16* Vg = Vtb + (size_t)bh * 131072 + s0;
#pragma unroll
        for (int i = 0; i < 4; i++) {
            int L = i * 256 + tid;
            int row = L >> 3;
            int c = (L & 7) ^ (row & 7);
            gld16(Vg + row * 1024 + c * 8, Vs + i * 2048 + wv * 512);
        }
        __syncthreads();

        // S = Q K^T  (Q pre-scaled by 1/sqrt(dk))
        f32x4 S[4];
#pragma unroll
        for (int fn = 0; fn < 4; fn++) S[fn] = (f32x4){0.f, 0.f, 0.f, 0.f};
#pragma unroll
        for (int kk = 0; kk < 4; kk++) {
            bf16x8 aF = *(const bf16x8*)(Qs + (row_w + frow) * 128 + ((kk * 4 + fq) ^ swz) * 8);
#pragma unroll
            for (int fn = 0; fn < 4; fn++) {
                bf16x8 bF = *(const bf16x8*)(Ks + (fn * 16 + frow) * 128 + ((kk * 4 + fq) ^ swz) * 8);
                S[fn] = __builtin_amdgcn_mfma_f32_16x16x32_bf16(aF, bF, S[fn], 0, 0, 0);
            }
        }

        if (st == qi) {   // diagonal tile: mask s > t
#pragma unroll
            for (int fn = 0; fn < 4; fn++)
#pragma unroll
                for (int r = 0; r < 4; r++) {
                    int t = t0 + row_w + fq * 4 + r;
                    int s = s0 + fn * 16 + frow;
                    if (s > t) S[fn][r] = -1e30f;
                }
        }

        // online softmax per row
#pragma unroll
        for (int r = 0; r < 4; r++) {
            float mx = fmaxf(fmaxf(S[0][r], S[1][r]), fmaxf(S[2][r], S[3][r]));
            mx = fmaxf(mx, __shfl_xor(mx, 1));
            mx = fmaxf(mx, __shfl_xor(mx, 2));
            mx = fmaxf(mx, __shfl_xor(mx, 4));
            mx = fmaxf(mx, __shfl_xor(mx, 8));
            float mnew = fmaxf(mrow[r], mx);
            float alpha = __expf(mrow[r] - mnew);
            float rs = 0.f;
#pragma unroll
            for (int fn = 0; fn < 4; fn++) {
                float p = __expf(S[fn][r] - mnew);
                S[fn][r] = p;
                rs += p;
            }
            rs += __shfl_xor(rs, 1);
            rs += __shfl_xor(rs, 2);
            rs += __shfl_xor(rs, 4);
            rs += __shfl_xor(rs, 8);
            mrow[r] = mnew;
            lrow[r] = lrow[r] * alpha + rs;
#pragma unroll
            for (int fd = 0; fd < 8; fd++) Oacc[fd][r] *= alpha;
        }

        // P -> LDS (C-layout -> A-layout), per-wave region, swizzled; no barrier needed
#pragma unroll
        for (int fn = 0; fn < 4; fn++)
#pragma unroll
            for (int r = 0; r < 4; r++) {
                int pr = row_w + fq * 4 + r;
                int c = fn * 2 + (frow >> 3);
                Ps[pr * 64 + ((c ^ (pr & 7)) * 8) + (frow & 7)] = f2bf(S[fn][r]);
            }

        // O += P V
#pragma unroll
        for (int ks = 0; ks < 2; ks++) {
            int rr = row_w + frow;
            bf16x8 aP = *(const bf16x8*)(Ps + rr * 64 + ((ks * 4 + fq) ^ (rr & 7)) * 8);
#pragma unroll
            for (int fd = 0; fd < 8; fd++) {
                int vr = fd * 16 + frow;
                bf16x8 bV = *(const bf16x8*)(Vs + vr * 64 + ((ks * 4 + fq) ^ (vr & 7)) * 8);
                Oacc[fd] = __builtin_amdgcn_mfma_f32_16x16x32_bf16(aP, bV, Oacc[fd], 0, 0, 0);
            }
        }
    }

    if (partial) {
        // raw partial: O (un-normalized), m, l
        float* Od = PO + (size_t)cidx * 8192;
#pragma unroll
        for (int r = 0; r < 4; r++) {
            int row = row_w + fq * 4 + r;
#pragma unroll
            for (int fd = 0; fd < 8; fd++)
                Od[row * 128 + fd * 16 + frow] = Oacc[fd][r];
        }
        if (frow == 0) {
#pragma unroll
            for (int r = 0; r < 4; r++) {
                int row = row_w + fq * 4 + r;
                PML[cidx * 128 + row * 2] = mrow[r];
                PML[cidx * 128 + row * 2 + 1] = lrow[r];
            }
        }
    } else {
        // final: merge heads -> AOb [b*1024+t, h*128+d] bf16
        const int b = bh >> 4, h = bh & 15;
#pragma unroll
        for (int r = 0; r < 4; r++) {
            float rl = 1.0f / lrow[r];
            int t = t0 + row_w + fq * 4 + r;
#pragma unroll
            for (int fd = 0; fd < 8; fd++) {
                int col = h * 128 + fd * 16 + frow;
                AOb[((size_t)b * 1024 + t) * 2048 + col] = f2bf(Oacc[fd][r] * rl);
            }
        }
    }
}

// ---------------- merge the two s-chunks for qi >= 8 ----------------
__global__ __launch_bounds__(256) void attn_merge_kernel(
    const float* __restrict__ PO, const float* __restrict__ PML, u16* __restrict__ AOb) {
    const int idx = blockIdx.x;                // 0..255
    const int bh = idx >> 3, qi = 8 + (idx & 7);
    const int t0 = qi * 64;
    const int b = bh >> 4, h = bh & 15;
    const int tid = threadIdx.x;
    const int row = tid >> 2, cg = tid & 3;    // 64 rows x 4 col-groups of 32
    const float* O0 = PO + (size_t)idx * 8192;
    const float* O1 = PO + (size_t)(256 + idx) * 8192;
    float m0 = PML[idx * 128 + row * 2],        l0 = PML[idx * 128 + row * 2 + 1];
    float m1 = PML[(256 + idx) * 128 + row * 2], l1 = PML[(256 + idx) * 128 + row * 2 + 1];
    float mm = fmaxf(m0, m1);
    float w0 = __expf(m0 - mm), w1 = __expf(m1 - mm);
    float inv = 1.0f / (l0 * w0 + l1 * w1);
    u16* dst = AOb + ((size_t)b * 1024 + t0 + row) * 2048 + h * 128 + cg * 32;
#pragma unroll
    for (int j = 0; j < 8; j++) {
        f32x4 a = *(const f32x4*)(O0 + row * 128 + cg * 32 + j * 4);
        f32x4 c = *(const f32x4*)(O1 + row * 128 + cg * 32 + j * 4);
        u16x4 o = { f2bf((a.x * w0 + c.x * w1) * inv), f2bf((a.y * w0 + c.y * w1) * inv),
                    f2bf((a.z * w0 + c.z * w1) * inv), f2bf((a.w * w0 + c.w * w1) * inv) };
        *(u16x4*)(dst + j * 4) = o;
    }
}

extern "C" void kernel_launch(void* const* d_in, const int* in_sizes, int n_in,
                              void* d_out, int out_size, void* d_ws, size_t ws_size,
                              hipStream_t stream) {
    const float* x  = (const float*)d_in[0];
    const float* ck = (const float*)d_in[1];
    const float* cv = (const float*)d_in[2];
    const float* Wq = (const float*)d_in[3];
    const float* Wk = (const float*)d_in[4];
    const float* Wv = (const float*)d_in[5];
    const float* Wo = (const float*)d_in[6];

    float* out  = (float*)d_out;               // [2048, 2048]
    float* Kout = out + 4194304;               // [B,H,2048,128]
    float* Vout = out + 12582912;              // [B,H,2048,128]

    u16* xb   = (u16*)d_ws;                    // [2048,2048]
    u16* Wqkv = xb + 4194304;                  // [6144,2048] (dead after gemm0)
    u16* Wob  = Wqkv + 12582912;               // [2048,2048]
    u16* Qb   = Wob + 4194304;                 // [B,H,1024,128] (pre-scaled)
    u16* Kcb  = Qb + 4194304;                  // [B,H,1024,128]
    u16* Vtb  = Kcb + 4194304;                 // [B,H,128,1024]
    u16* AOb  = Vtb + 4194304;                 // [2048,2048]
    // attention partials overlaid on dead Wqkv region (25.1 MB; we use 17 MB)
    float* PO  = (float*)Wqkv;                 // 2*256*8192 floats
    float* PML = PO + 4194304;                 // 2*256*128 floats

    convall_kernel<<<4096, 256, 0, stream>>>(x, Wq, Wk, Wv, Wo, xb, Wqkv, Wob);
    cachek_kernel<<<1024, 256, 0, stream>>>(ck, Kout, Kcb);
    vtrans_kernel<<<dim3(32, 16, 2), 256, 0, stream>>>(cv, Vout, Vtb);

    gemm_qkv_kernel<<<dim3(48, 16), 256, 0, stream>>>(xb, Wqkv, Qb, Kout, Vout);
    attn_kernel<<<768, 256, 0, stream>>>(Qb, Kcb, Vtb, AOb, PO, PML);
    attn_merge_kernel<<<256, 256, 0, stream>>>(PO, PML, AOb);
    gemm_out_kernel<<<dim3(16, 32), 256, 0, stream>>>(AOb, Wob, out);
}

// Round 3
// 324.938 us; speedup vs baseline: 1.0511x; 1.0511x over previous
//
#include <hip/hip_runtime.h>

typedef unsigned short u16;
typedef short bf16x8 __attribute__((ext_vector_type(8)));
typedef float f32x4 __attribute__((ext_vector_type(4)));
typedef unsigned short u16x4 __attribute__((ext_vector_type(4)));

#define AS1 __attribute__((address_space(1)))
#define AS3 __attribute__((address_space(3)))

__device__ __forceinline__ u16 f2bf(float f) {
    unsigned u = __float_as_uint(f);
    u += 0x7fff + ((u >> 16) & 1);   // round-to-nearest-even
    return (u16)(u >> 16);
}

__device__ __forceinline__ void gld16(const void* g, void* l) {
    __builtin_amdgcn_global_load_lds((const AS1 void*)g, (AS3 void*)l, 16, 0, 0);
}

// ---------------- fused fp32 -> bf16 conversion for x, Wq, Wk, Wv, Wo ----------------
__global__ void convall_kernel(const float* __restrict__ x,  const float* __restrict__ wq,
                               const float* __restrict__ wk, const float* __restrict__ wv,
                               const float* __restrict__ wo,
                               u16* __restrict__ xb, u16* __restrict__ wqkv, u16* __restrict__ wob) {
    int t = blockIdx.x * 256 + threadIdx.x;
    const float* srcs[5] = { x, wq, wk, wv, wo };
    u16* dsts[5] = { xb, wqkv, wqkv + 4194304, wqkv + 8388608, wob };
#pragma unroll
    for (int r = 0; r < 5; r++) {
        f32x4 v = ((const f32x4*)srcs[r])[t];
        u16x4 o = { f2bf(v.x), f2bf(v.y), f2bf(v.z), f2bf(v.w) };
        ((u16x4*)dsts[r])[t] = o;
    }
}

// ---------------- cache_k: copy fp32 -> d_out K region + bf16 convert ----------------
__global__ void cachek_kernel(const float* __restrict__ ck, float* __restrict__ kout,
                              u16* __restrict__ kcb) {
    const int n4 = (2 * 16 * 1024 * 128) / 4;   // 1048576
    int i = blockIdx.x * 256 + threadIdx.x;
    int stride = gridDim.x * 256;
    for (; i < n4; i += stride) {
        f32x4 v = ((const f32x4*)ck)[i];
        int bh = i >> 15;
        ((f32x4*)kout)[i + bh * 32768] = v;      // [bh,s<1024,d] -> [bh*2048+s,d]
        u16x4 o = { f2bf(v.x), f2bf(v.y), f2bf(v.z), f2bf(v.w) };
        ((u16x4*)kcb)[i] = o;
    }
}

// ---------------- cache_v: copy fp32 -> d_out V region + bf16 transpose [bh,d,s] ----------------
__global__ void vtrans_kernel(const float* __restrict__ cv, float* __restrict__ vout,
                              u16* __restrict__ vtb) {
    __shared__ u16 tile[64 * 65];
    const int bh = blockIdx.x;
    const int s0 = blockIdx.y * 64;
    const int d0 = blockIdx.z * 64;
    const float* src = cv + (size_t)bh * 1024 * 128;
#pragma unroll
    for (int i = 0; i < 16; i++) {
        int e = i * 256 + threadIdx.x;
        int sr = e >> 6, dc = e & 63;
        float v = src[(size_t)(s0 + sr) * 128 + d0 + dc];
        vout[((size_t)bh * 2048 + s0 + sr) * 128 + d0 + dc] = v;
        tile[sr * 65 + dc] = f2bf(v);
    }
    __syncthreads();
    u16* dst = vtb + (size_t)bh * 128 * 1024;
#pragma unroll
    for (int i = 0; i < 16; i++) {
        int e = i * 256 + threadIdx.x;
        int dr = e >> 6, sc = e & 63;
        dst[(size_t)(d0 + dr) * 1024 + s0 + sc] = tile[sc * 65 + dr];
    }
}

// ---------------- QKV GEMM: 8-phase 256x256 (T3+T4), 8 waves (2M x 4N), BK=64 ----------------
// Grid 24x8 = 192 blocks x 512 thr, LDS 128 KB dbuf, counted vmcnt(4) at phases 4/8
// (loads stay in flight across barriers -> intra-block latency hiding, works at 1 block/CU).
// Phase reads: {Alo+Blo(12), Bhi(4), Ahi(8), none} x 16 MFMA each.
// Stage schedule/half-K-tile computing u (buf u&1): ph1 A0(u+1) ph2 A1(u+1) ph3 B0(u+2)
// ph4 B1(u+2)+vmcnt(4). Each region overwritten >=1 barrier after its last read.
// vmcnt(4) => 8 of 12 in-flight loads done => the K-tile needed next is fully landed.
// Audit (R2): barrier counts uniform; all vmcnt waits satisfiable (12->4, 12->4, 8->0);
// all global/LDS addresses in bounds; tile-u+1 ds_reads issued after vmcnt(4)+2 barriers.
#define PH_COMPUTE(MO, NO, BREG) \
    __builtin_amdgcn_s_barrier(); \
    asm volatile("s_waitcnt lgkmcnt(0)" ::: "memory"); \
    __builtin_amdgcn_sched_barrier(0); \
    __builtin_amdgcn_s_setprio(1); \
    _Pragma("unroll") \
    for (int mf = 0; mf < 4; mf++) { \
        _Pragma("unroll") \
        for (int nf = 0; nf < 2; nf++) { \
            _Pragma("unroll") \
            for (int kk = 0; kk < 2; kk++) \
                acc[MO + mf][NO + nf] = __builtin_amdgcn_mfma_f32_16x16x32_bf16( \
                    aF[mf][kk], BREG[nf][kk], acc[MO + mf][NO + nf], 0, 0, 0); \
        } \
    } \
    __builtin_amdgcn_s_setprio(0); \
    __builtin_amdgcn_s_barrier();

#define HALF(P, S1, S2, S3, S4, VM) \
    { \
        _Pragma("unroll") \
        for (int mf = 0; mf < 4; mf++) \
            _Pragma("unroll") \
            for (int kk = 0; kk < 2; kk++) aF[mf][kk] = rdA(P, mf, kk); \
        _Pragma("unroll") \
        for (int nf = 0; nf < 2; nf++) \
            _Pragma("unroll") \
            for (int kk = 0; kk < 2; kk++) bLo[nf][kk] = rdB(P, nf, kk); \
        S1; \
        PH_COMPUTE(0, 0, bLo) \
        _Pragma("unroll") \
        for (int nf = 0; nf < 2; nf++) \
            _Pragma("unroll") \
            for (int kk = 0; kk < 2; kk++) bHi[nf][kk] = rdB(P, 2 + nf, kk); \
        S2; \
        PH_COMPUTE(0, 2, bHi) \
        _Pragma("unroll") \
        for (int mf = 0; mf < 4; mf++) \
            _Pragma("unroll") \
            for (int kk = 0; kk < 2; kk++) aF[mf][kk] = rdA(P, 4 + mf, kk); \
        S3; \
        PH_COMPUTE(4, 2, bHi) \
        S4; \
        VM; \
        PH_COMPUTE(4, 0, bLo) \
    }

__global__ __launch_bounds__(512, 2) void gemm_qkv_kernel(
    const u16* __restrict__ A, const u16* __restrict__ Bm,
    u16* __restrict__ qout, float* __restrict__ kout, float* __restrict__ vout) {
    __shared__ u16 Ab[2][16384];    // [buf][256 rows x 64] = 64 KB
    __shared__ u16 Bb[2][16384];    // 64 KB
    const int tid = threadIdx.x;
    const int lane = tid & 63, wv8 = tid >> 6;
    const int wrow = (wv8 >> 2) * 128;   // 0 / 128
    const int wcol = (wv8 & 3) * 64;     // 0 / 64 / 128 / 192
    const int m0 = blockIdx.y * 256, n0 = blockIdx.x * 256;
    const int frow = lane & 15, fq = lane >> 4;
    const int swz = frow & 7;

    f32x4 acc[8][4];
#pragma unroll
    for (int a = 0; a < 8; a++)
#pragma unroll
        for (int b = 0; b < 4; b++) acc[a][b] = (f32x4){0.f, 0.f, 0.f, 0.f};

    auto stA = [&](int kt, int half) {
        u16* dst = &Ab[kt & 1][half * 8192];
#pragma unroll
        for (int j = 0; j < 2; j++) {
            int L = j * 512 + tid;
            int row = L >> 3, c = (L & 7) ^ (row & 7);
            gld16(A + (size_t)(m0 + half * 128 + row) * 2048 + kt * 64 + c * 8,
                  dst + j * 4096 + wv8 * 512);
        }
    };
    auto stB = [&](int kt, int half) {
        u16* dst = &Bb[kt & 1][half * 8192];
#pragma unroll
        for (int j = 0; j < 2; j++) {
            int L = j * 512 + tid;
            int row = L >> 3, c = (L & 7) ^ (row & 7);
            gld16(Bm + (size_t)(n0 + half * 128 + row) * 2048 + kt * 64 + c * 8,
                  dst + j * 4096 + wv8 * 512);
        }
    };
    auto rdA = [&](int p, int mf, int kk) {
        int r = wrow + mf * 16 + frow;
        return *(const bf16x8*)(&Ab[p][r * 64 + (((kk << 2) + fq) ^ swz) * 8]);
    };
    auto rdB = [&](int p, int nf, int kk) {
        int r = wcol + nf * 16 + frow;
        return *(const bf16x8*)(&Bb[p][r * 64 + (((kk << 2) + fq) ^ swz) * 8]);
    };

    bf16x8 aF[4][2], bLo[2][2], bHi[2][2];

    // prologue: tile0 (4 half-tiles) + B(1); vmcnt(4) => tile0 fully landed
    stA(0, 0); stA(0, 1); stB(0, 0); stB(0, 1); stB(1, 0); stB(1, 1);
    asm volatile("s_waitcnt vmcnt(4)" ::: "memory");
    __builtin_amdgcn_s_barrier();

    for (int u = 0; u < 30; u += 2) {
        HALF(0, stA(u + 1, 0), stA(u + 1, 1), stB(u + 2, 0), stB(u + 2, 1),
             asm volatile("s_waitcnt vmcnt(4)" ::: "memory"))
        HALF(1, stA(u + 2, 0), stA(u + 2, 1), stB(u + 3, 0), stB(u + 3, 1),
             asm volatile("s_waitcnt vmcnt(4)" ::: "memory"))
    }
    // peeled tiles 30,31 (no more staging past K)
    HALF(0, stA(31, 0), stA(31, 1), (void)0, (void)0,
         asm volatile("s_waitcnt vmcnt(0)" ::: "memory"))
    HALF(1, (void)0, (void)0, (void)0, (void)0, (void)0)

    // epilogue: scatter Q (bf16, pre-scaled) / K / V (fp32 cache slots 1024..2047)
#pragma unroll
    for (int fm = 0; fm < 8; fm++) {
#pragma unroll
        for (int fn = 0; fn < 4; fn++) {
#pragma unroll
            for (int r = 0; r < 4; r++) {
                int m = m0 + wrow + fm * 16 + fq * 4 + r;
                int n = n0 + wcol + fn * 16 + frow;
                float v = acc[fm][fn][r];
                int b = m >> 10, t = m & 1023;
                int sect = n >> 11, nn = n & 2047;
                int h = nn >> 7, d = nn & 127;
                size_t bh = (size_t)(b * 16 + h);
                if (sect == 0)
                    qout[(bh * 1024 + t) * 128 + d] = f2bf(v * 0.08838834764831843f);
                else if (sect == 1)
                    kout[(bh * 2048 + 1024 + t) * 128 + d] = v;
                else
                    vout[(bh * 2048 + 1024 + t) * 128 + d] = v;
            }
        }
    }
}

// ---------------- out-proj GEMM: C[m,n] = sum_k A[m,k]*B[n,k], K=2048 ----------------
// 64x128 tile, 4 waves (each 64x32), BK=64, XOR-swizzled LDS (24 KB -> 6 blocks/CU).
// Kept: 512 blocks = 2/CU resident; 8-phase grid would be 64 blocks (25% fill).
__global__ __launch_bounds__(256) void gemm_out_kernel(
    const u16* __restrict__ A, const u16* __restrict__ Bm, float* __restrict__ cout) {
    __shared__ u16 As[64 * 64];     // 8 KB
    __shared__ u16 Bs[128 * 64];    // 16 KB
    const int tid = threadIdx.x;
    const int lane = tid & 63, wv = tid >> 6;
    const int wn = wv * 32;
    const int m0 = blockIdx.y * 64, n0 = blockIdx.x * 128;
    const int frow = lane & 15, fq = lane >> 4;
    const int swz = frow & 7;

    f32x4 acc[4][2];
#pragma unroll
    for (int a = 0; a < 4; a++)
#pragma unroll
        for (int b = 0; b < 2; b++) acc[a][b] = (f32x4){0.f, 0.f, 0.f, 0.f};

    for (int k0 = 0; k0 < 2048; k0 += 64) {
        __syncthreads();
#pragma unroll
        for (int i = 0; i < 2; i++) {
            int L = i * 256 + tid;             // A chunk 0..511
            int row = L >> 3;
            int c = (L & 7) ^ (row & 7);
            gld16(A + (size_t)(m0 + row) * 2048 + k0 + c * 8, As + i * 2048 + wv * 512);
        }
#pragma unroll
        for (int i = 0; i < 4; i++) {
            int L = i * 256 + tid;             // B chunk 0..1023
            int row = L >> 3;
            int c = (L & 7) ^ (row & 7);
            gld16(Bm + (size_t)(n0 + row) * 2048 + k0 + c * 8, Bs + i * 2048 + wv * 512);
        }
        __syncthreads();
#pragma unroll
        for (int kk = 0; kk < 2; kk++) {
            bf16x8 aF[4], bF[2];
#pragma unroll
            for (int f = 0; f < 4; f++)
                aF[f] = *(const bf16x8*)(As + (f * 16 + frow) * 64 + ((kk * 4 + fq) ^ swz) * 8);
#pragma unroll
            for (int f = 0; f < 2; f++)
                bF[f] = *(const bf16x8*)(Bs + (wn + f * 16 + frow) * 64 + ((kk * 4 + fq) ^ swz) * 8);
#pragma unroll
            for (int fm = 0; fm < 4; fm++)
#pragma unroll
                for (int fn = 0; fn < 2; fn++)
                    acc[fm][fn] = __builtin_amdgcn_mfma_f32_16x16x32_bf16(aF[fm], bF[fn], acc[fm][fn], 0, 0, 0);
        }
    }

#pragma unroll
    for (int fm = 0; fm < 4; fm++) {
#pragma unroll
        for (int fn = 0; fn < 2; fn++) {
#pragma unroll
            for (int r = 0; r < 4; r++) {
                int m = m0 + fm * 16 + fq * 4 + r;
                int n = n0 + wn + fn * 16 + frow;
                cout[(size_t)m * 2048 + n] = acc[fm][fn][r];
            }
        }
    }
}

// ---------------- flash attention, s-split for load balance ----------------
// 768 blocks, heavy-first:
//  bid<512: partial chunks of qi in [8,15]: qi = 15-(bid>>6), bh=(bid&63)>>1, c=bid&1.
//           chunk0 = tiles [0,ceil(n/2)), chunk1 = rest (incl. diagonal). Writes raw
//           m/l/O partials to workspace (overlaid on dead Wqkv region).
//  bid>=512: full blocks qi in [0,7] (loads 1..8), qi = 7-((bid-512)>>5), bh=(bid-512)&31.
// All block loads in [1..8.5] tiles; 768 blocks on 512 slots -> LPT-style balance.
// T5: setprio(1) around MFMA clusters (independent blocks share CUs -> arbitration helps).
__global__ __launch_bounds__(256) void attn_kernel(
    const u16* __restrict__ Qb, const u16* __restrict__ Kcb,
    const u16* __restrict__ Vtb, u16* __restrict__ AOb,
    float* __restrict__ PO, float* __restrict__ PML) {
    __shared__ u16 Qs[64 * 128];   // [t_local][d]  swizzled
    __shared__ u16 Ks[64 * 128];   // [s_local][d]  swizzled
    __shared__ u16 Vs[128 * 64];   // [d][s_local]  swizzled
    __shared__ u16 Ps[64 * 64];    // [t_local][s_local] swizzled
    const int bid = blockIdx.x;
    int bh, qi, st_begin, st_end, cidx;
    bool partial;
    if (bid < 512) {
        qi = 15 - (bid >> 6);
        int j = bid & 63;
        bh = j >> 1;
        int c = j & 1;
        int n = qi + 1, h0 = (n + 1) >> 1;
        st_begin = c ? h0 : 0;
        st_end = c ? n : h0;
        partial = true;
        cidx = c * 256 + bh * 8 + (qi - 8);
    } else {
        int j = bid - 512;
        qi = 7 - (j >> 5);
        bh = j & 31;
        st_begin = 0; st_end = qi + 1;
        partial = false; cidx = 0;
    }
    const int t0 = qi * 64;
    const int tid = threadIdx.x, lane = tid & 63, wv = tid >> 6;
    const int row_w = wv * 16;
    const int frow = lane & 15, fq = lane >> 4;
    const int swz = frow & 7;

    // stage Q (64x128 = 1024 chunks)
    const u16* Qg = Qb + ((size_t)bh * 1024 + t0) * 128;
#pragma unroll
    for (int i = 0; i < 4; i++) {
        int L = i * 256 + tid;
        int row = L >> 4;
        int c = (L & 15) ^ (row & 7);
        gld16(Qg + row * 128 + c * 8, Qs + i * 2048 + wv * 512);
    }

    float mrow[4], lrow[4];
    f32x4 Oacc[8];
#pragma unroll
    for (int r = 0; r < 4; r++) { mrow[r] = -1e30f; lrow[r] = 0.f; }
#pragma unroll
    for (int fd = 0; fd < 8; fd++) Oacc[fd] = (f32x4){0.f, 0.f, 0.f, 0.f};

    for (int st = st_begin; st < st_end; st++) {
        int s0 = st * 64;
        __syncthreads();
        const u16* Kg = Kcb + ((size_t)bh * 1024 + s0) * 128;
#pragma unroll
        for (int i = 0; i < 4; i++) {
            int L = i * 256 + tid;
            int row = L >> 4;
            int c = (L & 15) ^ (row & 7);
            gld16(Kg + row * 128 + c * 8, Ks + i * 2048 + wv * 512);
        }
        const u16* Vg = Vtb + (size_t)bh * 131072 + s0;
#pragma unroll
        for (int i = 0; i < 4; i++) {
            int L = i * 256 + tid;
            int row = L >> 3;
            int c = (L & 7) ^ (row & 7);
            gld16(Vg + row * 1024 + c * 8, Vs + i * 2048 + wv * 512);
        }
        __syncthreads();

        // S = Q K^T  (Q pre-scaled by 1/sqrt(dk))
        f32x4 S[4];
#pragma unroll
        for (int fn = 0; fn < 4; fn++) S[fn] = (f32x4){0.f, 0.f, 0.f, 0.f};
        __builtin_amdgcn_s_setprio(1);
#pragma unroll
        for (int kk = 0; kk < 4; kk++) {
            bf16x8 aF = *(const bf16x8*)(Qs + (row_w + frow) * 128 + ((kk * 4 + fq) ^ swz) * 8);
#pragma unroll
            for (int fn = 0; fn < 4; fn++) {
                bf16x8 bF = *(const bf16x8*)(Ks + (fn * 16 + frow) * 128 + ((kk * 4 + fq) ^ swz) * 8);
                S[fn] = __builtin_amdgcn_mfma_f32_16x16x32_bf16(aF, bF, S[fn], 0, 0, 0);
            }
        }
        __builtin_amdgcn_s_setprio(0);

        if (st == qi) {   // diagonal tile: mask s > t
#pragma unroll
            for (int fn = 0; fn < 4; fn++)
#pragma unroll
                for (int r = 0; r < 4; r++) {
                    int t = t0 + row_w + fq * 4 + r;
                    int s = s0 + fn * 16 + frow;
                    if (s > t) S[fn][r] = -1e30f;
                }
        }

        // online softmax per row
#pragma unroll
        for (int r = 0; r < 4; r++) {
            float mx = fmaxf(fmaxf(S[0][r], S[1][r]), fmaxf(S[2][r], S[3][r]));
            mx = fmaxf(mx, __shfl_xor(mx, 1));
            mx = fmaxf(mx, __shfl_xor(mx, 2));
            mx = fmaxf(mx, __shfl_xor(mx, 4));
            mx = fmaxf(mx, __shfl_xor(mx, 8));
            float mnew = fmaxf(mrow[r], mx);
            float alpha = __expf(mrow[r] - mnew);
            float rs = 0.f;
#pragma unroll
            for (int fn = 0; fn < 4; fn++) {
                float p = __expf(S[fn][r] - mnew);
                S[fn][r] = p;
                rs += p;
            }
            rs += __shfl_xor(rs, 1);
            rs += __shfl_xor(rs, 2);
            rs += __shfl_xor(rs, 4);
            rs += __shfl_xor(rs, 8);
            mrow[r] = mnew;
            lrow[r] = lrow[r] * alpha + rs;
#pragma unroll
            for (int fd = 0; fd < 8; fd++) Oacc[fd][r] *= alpha;
        }

        // P -> LDS (C-layout -> A-layout), per-wave region, swizzled; no barrier needed
#pragma unroll
        for (int fn = 0; fn < 4; fn++)
#pragma unroll
            for (int r = 0; r < 4; r++) {
                int pr = row_w + fq * 4 + r;
                int c = fn * 2 + (frow >> 3);
                Ps[pr * 64 + ((c ^ (pr & 7)) * 8) + (frow & 7)] = f2bf(S[fn][r]);
            }

        // O += P V
        __builtin_amdgcn_s_setprio(1);
#pragma unroll
        for (int ks = 0; ks < 2; ks++) {
            int rr = row_w + frow;
            bf16x8 aP = *(const bf16x8*)(Ps + rr * 64 + ((ks * 4 + fq) ^ (rr & 7)) * 8);
#pragma unroll
            for (int fd = 0; fd < 8; fd++) {
                int vr = fd * 16 + frow;
                bf16x8 bV = *(const bf16x8*)(Vs + vr * 64 + ((ks * 4 + fq) ^ (vr & 7)) * 8);
                Oacc[fd] = __builtin_amdgcn_mfma_f32_16x16x32_bf16(aP, bV, Oacc[fd], 0, 0, 0);
            }
        }
        __builtin_amdgcn_s_setprio(0);
    }

    if (partial) {
        // raw partial: O (un-normalized), m, l
        float* Od = PO + (size_t)cidx * 8192;
#pragma unroll
        for (int r = 0; r < 4; r++) {
            int row = row_w + fq * 4 + r;
#pragma unroll
            for (int fd = 0; fd < 8; fd++)
                Od[row * 128 + fd * 16 + frow] = Oacc[fd][r];
        }
        if (frow == 0) {
#pragma unroll
            for (int r = 0; r < 4; r++) {
                int row = row_w + fq * 4 + r;
                PML[cidx * 128 + row * 2] = mrow[r];
                PML[cidx * 128 + row * 2 + 1] = lrow[r];
            }
        }
    } else {
        // final: merge heads -> AOb [b*1024+t, h*128+d] bf16
        const int b = bh >> 4, h = bh & 15;
#pragma unroll
        for (int r = 0; r < 4; r++) {
            float rl = 1.0f / lrow[r];
            int t = t0 + row_w + fq * 4 + r;
#pragma unroll
            for (int fd = 0; fd < 8; fd++) {
                int col = h * 128 + fd * 16 + frow;
                AOb[((size_t)b * 1024 + t) * 2048 + col] = f2bf(Oacc[fd][r] * rl);
            }
        }
    }
}

// ---------------- merge the two s-chunks for qi >= 8 ----------------
__global__ __launch_bounds__(256) void attn_merge_kernel(
    const float* __restrict__ PO, const float* __restrict__ PML, u16* __restrict__ AOb) {
    const int idx = blockIdx.x;                // 0..255
    const int bh = idx >> 3, qi = 8 + (idx & 7);
    const int t0 = qi * 64;
    const int b = bh >> 4, h = bh & 15;
    const int tid = threadIdx.x;
    const int row = tid >> 2, cg = tid & 3;    // 64 rows x 4 col-groups of 32
    const float* O0 = PO + (size_t)idx * 8192;
    const float* O1 = PO + (size_t)(256 + idx) * 8192;
    float m0 = PML[idx * 128 + row * 2],        l0 = PML[idx * 128 + row * 2 + 1];
    float m1 = PML[(256 + idx) * 128 + row * 2], l1 = PML[(256 + idx) * 128 + row * 2 + 1];
    float mm = fmaxf(m0, m1);
    float w0 = __expf(m0 - mm), w1 = __expf(m1 - mm);
    float inv = 1.0f / (l0 * w0 + l1 * w1);
    u16* dst = AOb + ((size_t)b * 1024 + t0 + row) * 2048 + h * 128 + cg * 32;
#pragma unroll
    for (int j = 0; j < 8; j++) {
        f32x4 a = *(const f32x4*)(O0 + row * 128 + cg * 32 + j * 4);
        f32x4 c = *(const f32x4*)(O1 + row * 128 + cg * 32 + j * 4);
        u16x4 o = { f2bf((a.x * w0 + c.x * w1) * inv), f2bf((a.y * w0 + c.y * w1) * inv),
                    f2bf((a.z * w0 + c.z * w1) * inv), f2bf((a.w * w0 + c.w * w1) * inv) };
        *(u16x4*)(dst + j * 4) = o;
    }
}

extern "C" void kernel_launch(void* const* d_in, const int* in_sizes, int n_in,
                              void* d_out, int out_size, void* d_ws, size_t ws_size,
                              hipStream_t stream) {
    const float* x  = (const float*)d_in[0];
    const float* ck = (const float*)d_in[1];
    const float* cv = (const float*)d_in[2];
    const float* Wq = (const float*)d_in[3];
    const float* Wk = (const float*)d_in[4];
    const float* Wv = (const float*)d_in[5];
    const float* Wo = (const float*)d_in[6];

    float* out  = (float*)d_out;               // [2048, 2048]
    float* Kout = out + 4194304;               // [B,H,2048,128]
    float* Vout = out + 12582912;              // [B,H,2048,128]

    u16* xb   = (u16*)d_ws;                    // [2048,2048]
    u16* Wqkv = xb + 4194304;                  // [6144,2048] (dead after gemm0)
    u16* Wob  = Wqkv + 12582912;               // [2048,2048]
    u16* Qb   = Wob + 4194304;                 // [B,H,1024,128] (pre-scaled)
    u16* Kcb  = Qb + 4194304;                  // [B,H,1024,128]
    u16* Vtb  = Kcb + 4194304;                 // [B,H,128,1024]
    u16* AOb  = Vtb + 4194304;                 // [2048,2048]
    // attention partials overlaid on dead Wqkv region (25.1 MB; we use 17 MB)
    float* PO  = (float*)Wqkv;                 // 2*256*8192 floats
    float* PML = PO + 4194304;                 // 2*256*128 floats

    convall_kernel<<<4096, 256, 0, stream>>>(x, Wq, Wk, Wv, Wo, xb, Wqkv, Wob);
    cachek_kernel<<<1024, 256, 0, stream>>>(ck, Kout, Kcb);
    vtrans_kernel<<<dim3(32, 16, 2), 256, 0, stream>>>(cv, Vout, Vtb);

    gemm_qkv_kernel<<<dim3(24, 8), 512, 0, stream>>>(xb, Wqkv, Qb, Kout, Vout);
    attn_kernel<<<768, 256, 0, stream>>>(Qb, Kcb, Vtb, AOb, PO, PML);
    attn_merge_kernel<<<256, 256, 0, stream>>>(PO, PML, AOb);
    gemm_out_kernel<<<dim3(16, 32), 256, 0, stream>>>(AOb, Wob, out);
}

// Round 5
// 315.741 us; speedup vs baseline: 1.0817x; 1.0291x over previous
//
#include <hip/hip_runtime.h>

typedef unsigned short u16;
typedef short bf16x8 __attribute__((ext_vector_type(8)));
typedef float f32x4 __attribute__((ext_vector_type(4)));
typedef unsigned short u16x4 __attribute__((ext_vector_type(4)));

#define AS1 __attribute__((address_space(1)))
#define AS3 __attribute__((address_space(3)))

__device__ __forceinline__ u16 f2bf(float f) {
    unsigned u = __float_as_uint(f);
    u += 0x7fff + ((u >> 16) & 1);   // round-to-nearest-even
    return (u16)(u >> 16);
}

__device__ __forceinline__ void gld16(const void* g, void* l) {
    __builtin_amdgcn_global_load_lds((const AS1 void*)g, (AS3 void*)l, 16, 0, 0);
}

// ---------------- fused fp32 -> bf16 conversion for x, Wq, Wk, Wv, Wo ----------------
__global__ void convall_kernel(const float* __restrict__ x,  const float* __restrict__ wq,
                               const float* __restrict__ wk, const float* __restrict__ wv,
                               const float* __restrict__ wo,
                               u16* __restrict__ xb, u16* __restrict__ wqkv, u16* __restrict__ wob) {
    int t = blockIdx.x * 256 + threadIdx.x;
    const float* srcs[5] = { x, wq, wk, wv, wo };
    u16* dsts[5] = { xb, wqkv, wqkv + 4194304, wqkv + 8388608, wob };
#pragma unroll
    for (int r = 0; r < 5; r++) {
        f32x4 v = ((const f32x4*)srcs[r])[t];
        u16x4 o = { f2bf(v.x), f2bf(v.y), f2bf(v.z), f2bf(v.w) };
        ((u16x4*)dsts[r])[t] = o;
    }
}

// ---------------- cache_k: copy fp32 -> d_out K region + bf16 convert ----------------
__global__ void cachek_kernel(const float* __restrict__ ck, float* __restrict__ kout,
                              u16* __restrict__ kcb) {
    const int n4 = (2 * 16 * 1024 * 128) / 4;   // 1048576
    int i = blockIdx.x * 256 + threadIdx.x;
    int stride = gridDim.x * 256;
    for (; i < n4; i += stride) {
        f32x4 v = ((const f32x4*)ck)[i];
        int bh = i >> 15;
        ((f32x4*)kout)[i + bh * 32768] = v;      // [bh,s<1024,d] -> [bh*2048+s,d]
        u16x4 o = { f2bf(v.x), f2bf(v.y), f2bf(v.z), f2bf(v.w) };
        ((u16x4*)kcb)[i] = o;
    }
}

// ---------------- cache_v: copy fp32 -> d_out V region + bf16 transpose [bh,d,s] ----------------
__global__ void vtrans_kernel(const float* __restrict__ cv, float* __restrict__ vout,
                              u16* __restrict__ vtb) {
    __shared__ u16 tile[64 * 65];
    const int bh = blockIdx.x;
    const int s0 = blockIdx.y * 64;
    const int d0 = blockIdx.z * 64;
    const float* src = cv + (size_t)bh * 1024 * 128;
#pragma unroll
    for (int i = 0; i < 16; i++) {
        int e = i * 256 + threadIdx.x;
        int sr = e >> 6, dc = e & 63;
        float v = src[(size_t)(s0 + sr) * 128 + d0 + dc];
        vout[((size_t)bh * 2048 + s0 + sr) * 128 + d0 + dc] = v;
        tile[sr * 65 + dc] = f2bf(v);
    }
    __syncthreads();
    u16* dst = vtb + (size_t)bh * 128 * 1024;
#pragma unroll
    for (int i = 0; i < 16; i++) {
        int e = i * 256 + threadIdx.x;
        int dr = e >> 6, sc = e & 63;
        dst[(size_t)(d0 + dr) * 1024 + s0 + sc] = tile[sc * 65 + dr];
    }
}

// ---------------- QKV GEMM: 8-phase 256x192 (T3+T4), 8 waves (2M x 4N), BK=64 ----------------
// Grid 32x8 = 256 blocks = exactly 1/CU (100% fill; the BN=256 version left 64 CUs idle).
// Wave tile 128x48 (3 N-fragments). LDS 112 KB dbuf.
// Phases/K-tile: {MloN01:16, MloN2:8, MhiN2:8, MhiN01:16} MFMA = 48/wave/K-tile.
// Staging/K-tile: A half0(2 gld16), A half1(2), B 3x64-row chunks (1 gld16 each) = 7.
// vmcnt ledger: prologue 10 -> wait(3) lands tile0 (A0:4 + B0:3 complete, B1:3 in flight);
// steady 3+7=10 -> wait(3) completes B(u+1)+A(u+1) => tile u+1 fully landed, 3 remain;
// peel (tiles 30,31): 3+4=7 -> wait(0). Overwrite safety: stB(u+2) writes Bb[u&1] but is
// issued >= 2 barriers after the last Bb[u&1] ds_read completes (lgkmcnt(0) before MFMA,
// closing barrier before the stage slot) -- same audited argument as the BN=256 version.
// R4 re-audit: barrier counts uniform; vmcnt ledger consistent; stB LDS linearization
// algebraically verified (wv8*512+lane*8 == row*64+(lane&7)*8, XOR recovered on read);
// all bounds in range. Identical resubmit after infra double-failure (round-2->3 precedent).
#define PH_COMPUTE(MO, NO, NN, BREG) \
    __builtin_amdgcn_s_barrier(); \
    asm volatile("s_waitcnt lgkmcnt(0)" ::: "memory"); \
    __builtin_amdgcn_sched_barrier(0); \
    __builtin_amdgcn_s_setprio(1); \
    _Pragma("unroll") \
    for (int mf = 0; mf < 4; mf++) { \
        _Pragma("unroll") \
        for (int nf = 0; nf < NN; nf++) { \
            _Pragma("unroll") \
            for (int kk = 0; kk < 2; kk++) \
                acc[MO + mf][NO + nf] = __builtin_amdgcn_mfma_f32_16x16x32_bf16( \
                    aF[mf][kk], BREG[nf][kk], acc[MO + mf][NO + nf], 0, 0, 0); \
        } \
    } \
    __builtin_amdgcn_s_setprio(0); \
    __builtin_amdgcn_s_barrier();

#define HALF(P, S1, S2, S3, VM) \
    { \
        _Pragma("unroll") \
        for (int mf = 0; mf < 4; mf++) \
            _Pragma("unroll") \
            for (int kk = 0; kk < 2; kk++) aF[mf][kk] = rdA(P, mf, kk); \
        _Pragma("unroll") \
        for (int nf = 0; nf < 2; nf++) \
            _Pragma("unroll") \
            for (int kk = 0; kk < 2; kk++) b01[nf][kk] = rdB(P, nf, kk); \
        S1; \
        PH_COMPUTE(0, 0, 2, b01) \
        _Pragma("unroll") \
        for (int kk = 0; kk < 2; kk++) b2[0][kk] = rdB(P, 2, kk); \
        S2; \
        PH_COMPUTE(0, 2, 1, b2) \
        _Pragma("unroll") \
        for (int mf = 0; mf < 4; mf++) \
            _Pragma("unroll") \
            for (int kk = 0; kk < 2; kk++) aF[mf][kk] = rdA(P, 4 + mf, kk); \
        S3; \
        PH_COMPUTE(4, 2, 1, b2) \
        VM; \
        PH_COMPUTE(4, 0, 2, b01) \
    }

__global__ __launch_bounds__(512, 2) void gemm_qkv_kernel(
    const u16* __restrict__ A, const u16* __restrict__ Bm,
    u16* __restrict__ qout, float* __restrict__ kout, float* __restrict__ vout) {
    __shared__ u16 Ab[2][16384];    // [buf][256 rows x 64] = 64 KB
    __shared__ u16 Bb[2][12288];    // [buf][192 rows x 64] = 48 KB
    const int tid = threadIdx.x;
    const int lane = tid & 63, wv8 = tid >> 6;
    const int wrow = (wv8 >> 2) * 128;   // 0 / 128
    const int wcol = (wv8 & 3) * 48;     // 0 / 48 / 96 / 144
    const int m0 = blockIdx.y * 256, n0 = blockIdx.x * 192;
    const int frow = lane & 15, fq = lane >> 4;
    const int swz = frow & 7;

    f32x4 acc[8][3];
#pragma unroll
    for (int a = 0; a < 8; a++)
#pragma unroll
        for (int b = 0; b < 3; b++) acc[a][b] = (f32x4){0.f, 0.f, 0.f, 0.f};

    auto stA = [&](int kt, int half) {
        u16* dst = &Ab[kt & 1][half * 8192];
#pragma unroll
        for (int j = 0; j < 2; j++) {
            int L = j * 512 + tid;
            int row = L >> 3, c = (L & 7) ^ (row & 7);
            gld16(A + (size_t)(m0 + half * 128 + row) * 2048 + kt * 64 + c * 8,
                  dst + j * 4096 + wv8 * 512);
        }
    };
    auto stB = [&](int kt, int ch) {              // one 64-row chunk = 1 gld16/thread
        u16* dst = &Bb[kt & 1][ch * 4096];
        int row = tid >> 3, c = (tid & 7) ^ (row & 7);
        gld16(Bm + (size_t)(n0 + ch * 64 + row) * 2048 + kt * 64 + c * 8,
              dst + wv8 * 512);
    };
    auto rdA = [&](int p, int mf, int kk) {
        int r = wrow + mf * 16 + frow;
        return *(const bf16x8*)(&Ab[p][r * 64 + (((kk << 2) + fq) ^ swz) * 8]);
    };
    auto rdB = [&](int p, int nf, int kk) {
        int r = wcol + nf * 16 + frow;
        return *(const bf16x8*)(&Bb[p][r * 64 + (((kk << 2) + fq) ^ swz) * 8]);
    };

    bf16x8 aF[4][2], b01[2][2], b2[1][2];

    // prologue: tile0 (A 2 halves + B 3 chunks) + B(1); wait(3) => tile0 fully landed
    stA(0, 0); stA(0, 1); stB(0, 0); stB(0, 1); stB(0, 2);
    stB(1, 0); stB(1, 1); stB(1, 2);
    asm volatile("s_waitcnt vmcnt(3)" ::: "memory");
    __builtin_amdgcn_s_barrier();

    for (int u = 0; u < 30; u += 2) {
        HALF(0, stA(u + 1, 0), stA(u + 1, 1),
             (stB(u + 2, 0), stB(u + 2, 1), stB(u + 2, 2)),
             asm volatile("s_waitcnt vmcnt(3)" ::: "memory"))
        HALF(1, stA(u + 2, 0), stA(u + 2, 1),
             (stB(u + 3, 0), stB(u + 3, 1), stB(u + 3, 2)),
             asm volatile("s_waitcnt vmcnt(3)" ::: "memory"))
    }
    // peeled tiles 30,31 (no staging past K)
    HALF(0, stA(31, 0), stA(31, 1), (void)0,
         asm volatile("s_waitcnt vmcnt(0)" ::: "memory"))
    HALF(1, (void)0, (void)0, (void)0, (void)0)

    // epilogue: scatter Q (bf16, pre-scaled) / K / V (fp32 cache slots 1024..2047)
#pragma unroll
    for (int fm = 0; fm < 8; fm++) {
#pragma unroll
        for (int fn = 0; fn < 3; fn++) {
#pragma unroll
            for (int r = 0; r < 4; r++) {
                int m = m0 + wrow + fm * 16 + fq * 4 + r;
                int n = n0 + wcol + fn * 16 + frow;
                float v = acc[fm][fn][r];
                int b = m >> 10, t = m & 1023;
                int sect = n >> 11, nn = n & 2047;
                int h = nn >> 7, d = nn & 127;
                size_t bh = (size_t)(b * 16 + h);
                if (sect == 0)
                    qout[(bh * 1024 + t) * 128 + d] = f2bf(v * 0.08838834764831843f);
                else if (sect == 1)
                    kout[(bh * 2048 + 1024 + t) * 128 + d] = v;
                else
                    vout[(bh * 2048 + 1024 + t) * 128 + d] = v;
            }
        }
    }
}

// ---------------- out-proj GEMM: C[m,n] = sum_k A[m,k]*B[n,k], K=2048 ----------------
// 64x128 tile, 4 waves (each 64x32), BK=64, XOR-swizzled LDS (24 KB -> 6 blocks/CU).
// Kept: 512 blocks = 2/CU resident; 8-phase grid would be 64 blocks (25% fill).
__global__ __launch_bounds__(256) void gemm_out_kernel(
    const u16* __restrict__ A, const u16* __restrict__ Bm, float* __restrict__ cout) {
    __shared__ u16 As[64 * 64];     // 8 KB
    __shared__ u16 Bs[128 * 64];    // 16 KB
    const int tid = threadIdx.x;
    const int lane = tid & 63, wv = tid >> 6;
    const int wn = wv * 32;
    const int m0 = blockIdx.y * 64, n0 = blockIdx.x * 128;
    const int frow = lane & 15, fq = lane >> 4;
    const int swz = frow & 7;

    f32x4 acc[4][2];
#pragma unroll
    for (int a = 0; a < 4; a++)
#pragma unroll
        for (int b = 0; b < 2; b++) acc[a][b] = (f32x4){0.f, 0.f, 0.f, 0.f};

    for (int k0 = 0; k0 < 2048; k0 += 64) {
        __syncthreads();
#pragma unroll
        for (int i = 0; i < 2; i++) {
            int L = i * 256 + tid;             // A chunk 0..511
            int row = L >> 3;
            int c = (L & 7) ^ (row & 7);
            gld16(A + (size_t)(m0 + row) * 2048 + k0 + c * 8, As + i * 2048 + wv * 512);
        }
#pragma unroll
        for (int i = 0; i < 4; i++) {
            int L = i * 256 + tid;             // B chunk 0..1023
            int row = L >> 3;
            int c = (L & 7) ^ (row & 7);
            gld16(Bm + (size_t)(n0 + row) * 2048 + k0 + c * 8, Bs + i * 2048 + wv * 512);
        }
        __syncthreads();
#pragma unroll
        for (int kk = 0; kk < 2; kk++) {
            bf16x8 aF[4], bF[2];
#pragma unroll
            for (int f = 0; f < 4; f++)
                aF[f] = *(const bf16x8*)(As + (f * 16 + frow) * 64 + ((kk * 4 + fq) ^ swz) * 8);
#pragma unroll
            for (int f = 0; f < 2; f++)
                bF[f] = *(const bf16x8*)(Bs + (wn + f * 16 + frow) * 64 + ((kk * 4 + fq) ^ swz) * 8);
#pragma unroll
            for (int fm = 0; fm < 4; fm++)
#pragma unroll
                for (int fn = 0; fn < 2; fn++)
                    acc[fm][fn] = __builtin_amdgcn_mfma_f32_16x16x32_bf16(aF[fm], bF[fn], acc[fm][fn], 0, 0, 0);
        }
    }

#pragma unroll
    for (int fm = 0; fm < 4; fm++) {
#pragma unroll
        for (int fn = 0; fn < 2; fn++) {
#pragma unroll
            for (int r = 0; r < 4; r++) {
                int m = m0 + fm * 16 + fq * 4 + r;
                int n = n0 + wn + fn * 16 + frow;
                cout[(size_t)m * 2048 + n] = acc[fm][fn][r];
            }
        }
    }
}

// ---------------- flash attention, s-split for load balance ----------------
// 768 blocks, heavy-first:
//  bid<512: partial chunks of qi in [8,15]: qi = 15-(bid>>6), bh=(bid&63)>>1, c=bid&1.
//           chunk0 = tiles [0,ceil(n/2)), chunk1 = rest (incl. diagonal). Writes raw
//           m/l/O partials to workspace (overlaid on dead Wqkv region).
//  bid>=512: full blocks qi in [0,7] (loads 1..8), qi = 7-((bid-512)>>5), bh=(bid-512)&31.
// All block loads in [1..8.5] tiles; 768 blocks on 512 slots -> LPT-style balance.
// R3: setprio removed -- waves here are barrier-locked per block (m190 lockstep regime,
// where T5 measured null-to-negative); round-1 arithmetic showed ~15us total regression.
__global__ __launch_bounds__(256) void attn_kernel(
    const u16* __restrict__ Qb, const u16* __restrict__ Kcb,
    const u16* __restrict__ Vtb, u16* __restrict__ AOb,
    float* __restrict__ PO, float* __restrict__ PML) {
    __shared__ u16 Qs[64 * 128];   // [t_local][d]  swizzled
    __shared__ u16 Ks[64 * 128];   // [s_local][d]  swizzled
    __shared__ u16 Vs[128 * 64];   // [d][s_local]  swizzled
    __shared__ u16 Ps[64 * 64];    // [t_local][s_local] swizzled
    const int bid = blockIdx.x;
    int bh, qi, st_begin, st_end, cidx;
    bool partial;
    if (bid < 512) {
        qi = 15 - (bid >> 6);
        int j = bid & 63;
        bh = j >> 1;
        int c = j & 1;
        int n = qi + 1, h0 = (n + 1) >> 1;
        st_begin = c ? h0 : 0;
        st_end = c ? n : h0;
        partial = true;
        cidx = c * 256 + bh * 8 + (qi - 8);
    } else {
        int j = bid - 512;
        qi = 7 - (j >> 5);
        bh = j & 31;
        st_begin = 0; st_end = qi + 1;
        partial = false; cidx = 0;
    }
    const int t0 = qi * 64;
    const int tid = threadIdx.x, lane = tid & 63, wv = tid >> 6;
    const int row_w = wv * 16;
    const int frow = lane & 15, fq = lane >> 4;
    const int swz = frow & 7;

    // stage Q (64x128 = 1024 chunks)
    const u16* Qg = Qb + ((size_t)bh * 1024 + t0) * 128;
#pragma unroll
    for (int i = 0; i < 4; i++) {
        int L = i * 256 + tid;
        int row = L >> 4;
        int c = (L & 15) ^ (row & 7);
        gld16(Qg + row * 128 + c * 8, Qs + i * 2048 + wv * 512);
    }

    float mrow[4], lrow[4];
    f32x4 Oacc[8];
#pragma unroll
    for (int r = 0; r < 4; r++) { mrow[r] = -1e30f; lrow[r] = 0.f; }
#pragma unroll
    for (int fd = 0; fd < 8; fd++) Oacc[fd] = (f32x4){0.f, 0.f, 0.f, 0.f};

    for (int st = st_begin; st < st_end; st++) {
        int s0 = st * 64;
        __syncthreads();
        const u16* Kg = Kcb + ((size_t)bh * 1024 + s0) * 128;
#pragma unroll
        for (int i = 0; i < 4; i++) {
            int L = i * 256 + tid;
            int row = L >> 4;
            int c = (L & 15) ^ (row & 7);
            gld16(Kg + row * 128 + c * 8, Ks + i * 2048 + wv * 512);
        }
        const u16* Vg = Vtb + (size_t)bh * 131072 + s0;
#pragma unroll
        for (int i = 0; i < 4; i++) {
            int L = i * 256 + tid;
            int row = L >> 3;
            int c = (L & 7) ^ (row & 7);
            gld16(Vg + row * 1024 + c * 8, Vs + i * 2048 + wv * 512);
        }
        __syncthreads();

        // S = Q K^T  (Q pre-scaled by 1/sqrt(dk))
        f32x4 S[4];
#pragma unroll
        for (int fn = 0; fn < 4; fn++) S[fn] = (f32x4){0.f, 0.f, 0.f, 0.f};
#pragma unroll
        for (int kk = 0; kk < 4; kk++) {
            bf16x8 aF = *(const bf16x8*)(Qs + (row_w + frow) * 128 + ((kk * 4 + fq) ^ swz) * 8);
#pragma unroll
            for (int fn = 0; fn < 4; fn++) {
                bf16x8 bF = *(const bf16x8*)(Ks + (fn * 16 + frow) * 128 + ((kk * 4 + fq) ^ swz) * 8);
                S[fn] = __builtin_amdgcn_mfma_f32_16x16x32_bf16(aF, bF, S[fn], 0, 0, 0);
            }
        }

        if (st == qi) {   // diagonal tile: mask s > t
#pragma unroll
            for (int fn = 0; fn < 4; fn++)
#pragma unroll
                for (int r = 0; r < 4; r++) {
                    int t = t0 + row_w + fq * 4 + r;
                    int s = s0 + fn * 16 + frow;
                    if (s > t) S[fn][r] = -1e30f;
                }
        }

        // online softmax per row
#pragma unroll
        for (int r = 0; r < 4; r++) {
            float mx = fmaxf(fmaxf(S[0][r], S[1][r]), fmaxf(S[2][r], S[3][r]));
            mx = fmaxf(mx, __shfl_xor(mx, 1));
            mx = fmaxf(mx, __shfl_xor(mx, 2));
            mx = fmaxf(mx, __shfl_xor(mx, 4));
            mx = fmaxf(mx, __shfl_xor(mx, 8));
            float mnew = fmaxf(mrow[r], mx);
            float alpha = __expf(mrow[r] - mnew);
            float rs = 0.f;
#pragma unroll
            for (int fn = 0; fn < 4; fn++) {
                float p = __expf(S[fn][r] - mnew);
                S[fn][r] = p;
                rs += p;
            }
            rs += __shfl_xor(rs, 1);
            rs += __shfl_xor(rs, 2);
            rs += __shfl_xor(rs, 4);
            rs += __shfl_xor(rs, 8);
            mrow[r] = mnew;
            lrow[r] = lrow[r] * alpha + rs;
#pragma unroll
            for (int fd = 0; fd < 8; fd++) Oacc[fd][r] *= alpha;
        }

        // P -> LDS (C-layout -> A-layout), per-wave region, swizzled; no barrier needed
#pragma unroll
        for (int fn = 0; fn < 4; fn++)
#pragma unroll
            for (int r = 0; r < 4; r++) {
                int pr = row_w + fq * 4 + r;
                int c = fn * 2 + (frow >> 3);
                Ps[pr * 64 + ((c ^ (pr & 7)) * 8) + (frow & 7)] = f2bf(S[fn][r]);
            }

        // O += P V
#pragma unroll
        for (int ks = 0; ks < 2; ks++) {
            int rr = row_w + frow;
            bf16x8 aP = *(const bf16x8*)(Ps + rr * 64 + ((ks * 4 + fq) ^ (rr & 7)) * 8);
#pragma unroll
            for (int fd = 0; fd < 8; fd++) {
                int vr = fd * 16 + frow;
                bf16x8 bV = *(const bf16x8*)(Vs + vr * 64 + ((ks * 4 + fq) ^ (vr & 7)) * 8);
                Oacc[fd] = __builtin_amdgcn_mfma_f32_16x16x32_bf16(aP, bV, Oacc[fd], 0, 0, 0);
            }
        }
    }

    if (partial) {
        // raw partial: O (un-normalized), m, l
        float* Od = PO + (size_t)cidx * 8192;
#pragma unroll
        for (int r = 0; r < 4; r++) {
            int row = row_w + fq * 4 + r;
#pragma unroll
            for (int fd = 0; fd < 8; fd++)
                Od[row * 128 + fd * 16 + frow] = Oacc[fd][r];
        }
        if (frow == 0) {
#pragma unroll
            for (int r = 0; r < 4; r++) {
                int row = row_w + fq * 4 + r;
                PML[cidx * 128 + row * 2] = mrow[r];
                PML[cidx * 128 + row * 2 + 1] = lrow[r];
            }
        }
    } else {
        // final: merge heads -> AOb [b*1024+t, h*128+d] bf16
        const int b = bh >> 4, h = bh & 15;
#pragma unroll
        for (int r = 0; r < 4; r++) {
            float rl = 1.0f / lrow[r];
            int t = t0 + row_w + fq * 4 + r;
#pragma unroll
            for (int fd = 0; fd < 8; fd++) {
                int col = h * 128 + fd * 16 + frow;
                AOb[((size_t)b * 1024 + t) * 2048 + col] = f2bf(Oacc[fd][r] * rl);
            }
        }
    }
}

// ---------------- merge the two s-chunks for qi >= 8 ----------------
__global__ __launch_bounds__(256) void attn_merge_kernel(
    const float* __restrict__ PO, const float* __restrict__ PML, u16* __restrict__ AOb) {
    const int idx = blockIdx.x;                // 0..255
    const int bh = idx >> 3, qi = 8 + (idx & 7);
    const int t0 = qi * 64;
    const int b = bh >> 4, h = bh & 15;
    const int tid = threadIdx.x;
    const int row = tid >> 2, cg = tid & 3;    // 64 rows x 4 col-groups of 32
    const float* O0 = PO + (size_t)idx * 8192;
    const float* O1 = PO + (size_t)(256 + idx) * 8192;
    float m0 = PML[idx * 128 + row * 2],        l0 = PML[idx * 128 + row * 2 + 1];
    float m1 = PML[(256 + idx) * 128 + row * 2], l1 = PML[(256 + idx) * 128 + row * 2 + 1];
    float mm = fmaxf(m0, m1);
    float w0 = __expf(m0 - mm), w1 = __expf(m1 - mm);
    float inv = 1.0f / (l0 * w0 + l1 * w1);
    u16* dst = AOb + ((size_t)b * 1024 + t0 + row) * 2048 + h * 128 + cg * 32;
#pragma unroll
    for (int j = 0; j < 8; j++) {
        f32x4 a = *(const f32x4*)(O0 + row * 128 + cg * 32 + j * 4);
        f32x4 c = *(const f32x4*)(O1 + row * 128 + cg * 32 + j * 4);
        u16x4 o = { f2bf((a.x * w0 + c.x * w1) * inv), f2bf((a.y * w0 + c.y * w1) * inv),
                    f2bf((a.z * w0 + c.z * w1) * inv), f2bf((a.w * w0 + c.w * w1) * inv) };
        *(u16x4*)(dst + j * 4) = o;
    }
}

extern "C" void kernel_launch(void* const* d_in, const int* in_sizes, int n_in,
                              void* d_out, int out_size, void* d_ws, size_t ws_size,
                              hipStream_t stream) {
    const float* x  = (const float*)d_in[0];
    const float* ck = (const float*)d_in[1];
    const float* cv = (const float*)d_in[2];
    const float* Wq = (const float*)d_in[3];
    const float* Wk = (const float*)d_in[4];
    const float* Wv = (const float*)d_in[5];
    const float* Wo = (const float*)d_in[6];

    float* out  = (float*)d_out;               // [2048, 2048]
    float* Kout = out + 4194304;               // [B,H,2048,128]
    float* Vout = out + 12582912;              // [B,H,2048,128]

    u16* xb   = (u16*)d_ws;                    // [2048,2048]
    u16* Wqkv = xb + 4194304;                  // [6144,2048] (dead after gemm0)
    u16* Wob  = Wqkv + 12582912;               // [2048,2048]
    u16* Qb   = Wob + 4194304;                 // [B,H,1024,128] (pre-scaled)
    u16* Kcb  = Qb + 4194304;                  // [B,H,1024,128]
    u16* Vtb  = Kcb + 4194304;                 // [B,H,128,1024]
    u16* AOb  = Vtb + 4194304;                 // [2048,2048]
    // attention partials overlaid on dead Wqkv region (25.1 MB; we use 17 MB)
    float* PO  = (float*)Wqkv;                 // 2*256*8192 floats
    float* PML = PO + 4194304;                 // 2*256*128 floats

    convall_kernel<<<4096, 256, 0, stream>>>(x, Wq, Wk, Wv, Wo, xb, Wqkv, Wob);
    cachek_kernel<<<1024, 256, 0, stream>>>(ck, Kout, Kcb);
    vtrans_kernel<<<dim3(32, 16, 2), 256, 0, stream>>>(cv, Vout, Vtb);

    gemm_qkv_kernel<<<dim3(32, 8), 512, 0, stream>>>(xb, Wqkv, Qb, Kout, Vout);
    attn_kernel<<<768, 256, 0, stream>>>(Qb, Kcb, Vtb, AOb, PO, PML);
    attn_merge_kernel<<<256, 256, 0, stream>>>(PO, PML, AOb);
    gemm_out_kernel<<<dim3(16, 32), 256, 0, stream>>>(AOb, Wob, out);
}

// Round 6
// 312.848 us; speedup vs baseline: 1.0917x; 1.0092x over previous
//
#include <hip/hip_runtime.h>

typedef unsigned short u16;
typedef short bf16x8 __attribute__((ext_vector_type(8)));
typedef float f32x4 __attribute__((ext_vector_type(4)));
typedef unsigned short u16x4 __attribute__((ext_vector_type(4)));

#define AS1 __attribute__((address_space(1)))
#define AS3 __attribute__((address_space(3)))

__device__ __forceinline__ u16 f2bf(float f) {
    unsigned u = __float_as_uint(f);
    u += 0x7fff + ((u >> 16) & 1);   // round-to-nearest-even
    return (u16)(u >> 16);
}

__device__ __forceinline__ void gld16(const void* g, void* l) {
    __builtin_amdgcn_global_load_lds((const AS1 void*)g, (AS3 void*)l, 16, 0, 0);
}

// ---------------- fused fp32 -> bf16 conversion for x, Wq, Wk, Wv, Wo ----------------
__global__ void convall_kernel(const float* __restrict__ x,  const float* __restrict__ wq,
                               const float* __restrict__ wk, const float* __restrict__ wv,
                               const float* __restrict__ wo,
                               u16* __restrict__ xb, u16* __restrict__ wqkv, u16* __restrict__ wob) {
    int t = blockIdx.x * 256 + threadIdx.x;
    const float* srcs[5] = { x, wq, wk, wv, wo };
    u16* dsts[5] = { xb, wqkv, wqkv + 4194304, wqkv + 8388608, wob };
#pragma unroll
    for (int r = 0; r < 5; r++) {
        f32x4 v = ((const f32x4*)srcs[r])[t];
        u16x4 o = { f2bf(v.x), f2bf(v.y), f2bf(v.z), f2bf(v.w) };
        ((u16x4*)dsts[r])[t] = o;
    }
}

// ---------------- cache_k: copy fp32 -> d_out K region + bf16 convert ----------------
__global__ void cachek_kernel(const float* __restrict__ ck, float* __restrict__ kout,
                              u16* __restrict__ kcb) {
    const int n4 = (2 * 16 * 1024 * 128) / 4;   // 1048576
    int i = blockIdx.x * 256 + threadIdx.x;
    int stride = gridDim.x * 256;
    for (; i < n4; i += stride) {
        f32x4 v = ((const f32x4*)ck)[i];
        int bh = i >> 15;
        ((f32x4*)kout)[i + bh * 32768] = v;      // [bh,s<1024,d] -> [bh*2048+s,d]
        u16x4 o = { f2bf(v.x), f2bf(v.y), f2bf(v.z), f2bf(v.w) };
        ((u16x4*)kcb)[i] = o;
    }
}

// ---------------- cache_v: copy fp32 -> d_out V region + bf16 transpose [bh,d,s] ----------------
__global__ void vtrans_kernel(const float* __restrict__ cv, float* __restrict__ vout,
                              u16* __restrict__ vtb) {
    __shared__ u16 tile[64 * 65];
    const int bh = blockIdx.x;
    const int s0 = blockIdx.y * 64;
    const int d0 = blockIdx.z * 64;
    const float* src = cv + (size_t)bh * 1024 * 128;
#pragma unroll
    for (int i = 0; i < 16; i++) {
        int e = i * 256 + threadIdx.x;
        int sr = e >> 6, dc = e & 63;
        float v = src[(size_t)(s0 + sr) * 128 + d0 + dc];
        vout[((size_t)bh * 2048 + s0 + sr) * 128 + d0 + dc] = v;
        tile[sr * 65 + dc] = f2bf(v);
    }
    __syncthreads();
    u16* dst = vtb + (size_t)bh * 128 * 1024;
#pragma unroll
    for (int i = 0; i < 16; i++) {
        int e = i * 256 + threadIdx.x;
        int dr = e >> 6, sc = e & 63;
        dst[(size_t)(d0 + dr) * 1024 + s0 + sc] = tile[sc * 65 + dr];
    }
}

// ---------------- QKV GEMM: 3-even-phase 256x192, 8 waves (4M x 2N), BK=64 ----------------
// R5 post-mortem: 16/8/8/16 MFMA phases left two windows too small to amortize the ~260cyc
// pair overhead (MfmaUtil 30.8%). New split: wave tile 64x96 (4mf x 6nf) -> 3 phases of
// exactly 16 MFMA per K-tile (3 barrier-pairs, was 4), A ds_reads 8/wave/tile (was 16).
// B TRIPLE-buffered (strict write-after-read safety: stage buffer never equals read buffer;
// 2-buffer B would put the B-stage in the same inter-barrier window as B-reads = latency race).
// LDS = Ab 2x32KB + Bb 3x24KB = 136 KB. Grid 32x8 = 256 blocks = 1/CU (100% fill).
// vmcnt ledger (identical to audited R5): prologue A0+B0+B1 = 10 -> wait(3) lands tile0,
// B1 in flight; steady: 3 + S1:2 + S2:2 + S3:3 = 10 -> wait(3) completes B(u+1)+A(u+1),
// leaves B(u+2):3; peel t=30: 3+4=7 -> wait(0); t=31: no stage. Loop unrolled x6 so all
// buffer indices (A parity 2, B mod 3) are compile-time (rule #20).
#define PH16(NF0) \
    __builtin_amdgcn_s_barrier(); \
    asm volatile("s_waitcnt lgkmcnt(0)" ::: "memory"); \
    __builtin_amdgcn_sched_barrier(0); \
    __builtin_amdgcn_s_setprio(1); \
    _Pragma("unroll") \
    for (int mf = 0; mf < 4; mf++) { \
        _Pragma("unroll") \
        for (int nq = 0; nq < 2; nq++) { \
            _Pragma("unroll") \
            for (int kk = 0; kk < 2; kk++) \
                acc[mf][NF0 + nq] = __builtin_amdgcn_mfma_f32_16x16x32_bf16( \
                    aF[mf][kk], bF[nq][kk], acc[mf][NF0 + nq], 0, 0, 0); \
        } \
    } \
    __builtin_amdgcn_s_setprio(0); \
    __builtin_amdgcn_s_barrier();

#define ITER(PA, PB, S1, S2, S3, VM) { \
    _Pragma("unroll") \
    for (int mf = 0; mf < 4; mf++) \
        _Pragma("unroll") \
        for (int kk = 0; kk < 2; kk++) aF[mf][kk] = rdA(PA, mf, kk); \
    _Pragma("unroll") \
    for (int nq = 0; nq < 2; nq++) \
        _Pragma("unroll") \
        for (int kk = 0; kk < 2; kk++) bF[nq][kk] = rdB(PB, nq, kk); \
    S1; \
    asm volatile("s_waitcnt lgkmcnt(8)" ::: "memory"); \
    PH16(0) \
    _Pragma("unroll") \
    for (int nq = 0; nq < 2; nq++) \
        _Pragma("unroll") \
        for (int kk = 0; kk < 2; kk++) bF[nq][kk] = rdB(PB, 2 + nq, kk); \
    S2; \
    PH16(2) \
    _Pragma("unroll") \
    for (int nq = 0; nq < 2; nq++) \
        _Pragma("unroll") \
        for (int kk = 0; kk < 2; kk++) bF[nq][kk] = rdB(PB, 4 + nq, kk); \
    S3; \
    VM; \
    PH16(4) \
}

#define VM3 asm volatile("s_waitcnt vmcnt(3)" ::: "memory")

__global__ __launch_bounds__(512, 2) void gemm_qkv_kernel(
    const u16* __restrict__ A, const u16* __restrict__ Bm,
    u16* __restrict__ qout, float* __restrict__ kout, float* __restrict__ vout) {
    __shared__ u16 Ab[2][16384];    // [buf][256 rows x 64] = 64 KB
    __shared__ u16 Bb[3][12288];    // [buf][192 rows x 64] = 72 KB (triple-buffered)
    const int tid = threadIdx.x;
    const int lane = tid & 63, wv8 = tid >> 6;
    const int wrow = (wv8 >> 1) * 64;    // 0 / 64 / 128 / 192
    const int wcol = (wv8 & 1) * 96;     // 0 / 96
    const int m0 = blockIdx.y * 256, n0 = blockIdx.x * 192;
    const int frow = lane & 15, fq = lane >> 4;
    const int swz = frow & 7;

    f32x4 acc[4][6];
#pragma unroll
    for (int a = 0; a < 4; a++)
#pragma unroll
        for (int b = 0; b < 6; b++) acc[a][b] = (f32x4){0.f, 0.f, 0.f, 0.f};

    auto stA = [&](int buf, int kt, int half) {
        u16* dst = &Ab[buf][half * 8192];
#pragma unroll
        for (int j = 0; j < 2; j++) {
            int L = j * 512 + tid;
            int row = L >> 3, c = (L & 7) ^ (row & 7);
            gld16(A + (size_t)(m0 + half * 128 + row) * 2048 + kt * 64 + c * 8,
                  dst + j * 4096 + wv8 * 512);
        }
    };
    auto stB = [&](int buf, int kt, int ch) {     // one 64-row chunk = 1 gld16/thread
        u16* dst = &Bb[buf][ch * 4096];
        int row = tid >> 3, c = (tid & 7) ^ (row & 7);
        gld16(Bm + (size_t)(n0 + ch * 64 + row) * 2048 + kt * 64 + c * 8,
              dst + wv8 * 512);
    };
    auto rdA = [&](int p, int mf, int kk) {
        int r = wrow + mf * 16 + frow;
        return *(const bf16x8*)(&Ab[p][r * 64 + (((kk << 2) + fq) ^ swz) * 8]);
    };
    auto rdB = [&](int p, int nf, int kk) {
        int r = wcol + nf * 16 + frow;
        return *(const bf16x8*)(&Bb[p][r * 64 + (((kk << 2) + fq) ^ swz) * 8]);
    };

    bf16x8 aF[4][2], bF[2][2];

    // prologue: A(0) -> Ab[0], B(0) -> Bb[0], B(1) -> Bb[1]; wait(3) => tile0 landed
    stA(0, 0, 0); stA(0, 0, 1);
    stB(0, 0, 0); stB(0, 0, 1); stB(0, 0, 2);
    stB(1, 1, 0); stB(1, 1, 1); stB(1, 1, 2);
    VM3;
    __builtin_amdgcn_s_barrier();

    for (int u = 0; u < 30; u += 6) {
        ITER(0, 0, stA(1, u + 1, 0), stA(1, u + 1, 1),
             (stB(2, u + 2, 0), stB(2, u + 2, 1), stB(2, u + 2, 2)), VM3)
        ITER(1, 1, stA(0, u + 2, 0), stA(0, u + 2, 1),
             (stB(0, u + 3, 0), stB(0, u + 3, 1), stB(0, u + 3, 2)), VM3)
        ITER(0, 2, stA(1, u + 3, 0), stA(1, u + 3, 1),
             (stB(1, u + 4, 0), stB(1, u + 4, 1), stB(1, u + 4, 2)), VM3)
        ITER(1, 0, stA(0, u + 4, 0), stA(0, u + 4, 1),
             (stB(2, u + 5, 0), stB(2, u + 5, 1), stB(2, u + 5, 2)), VM3)
        ITER(0, 1, stA(1, u + 5, 0), stA(1, u + 5, 1),
             (stB(0, u + 6, 0), stB(0, u + 6, 1), stB(0, u + 6, 2)), VM3)
        ITER(1, 2, stA(0, u + 6, 0), stA(0, u + 6, 1),
             (stB(1, u + 7, 0), stB(1, u + 7, 1), stB(1, u + 7, 2)), VM3)
    }
    // peeled tiles 30 (Ab[0], Bb[0]) and 31 (Ab[1], Bb[1])
    ITER(0, 0, stA(1, 31, 0), stA(1, 31, 1), (void)0,
         asm volatile("s_waitcnt vmcnt(0)" ::: "memory"))
    ITER(1, 1, (void)0, (void)0, (void)0, (void)0)

    // epilogue: scatter Q (bf16, pre-scaled) / K / V (fp32 cache slots 1024..2047)
#pragma unroll
    for (int fm = 0; fm < 4; fm++) {
#pragma unroll
        for (int fn = 0; fn < 6; fn++) {
#pragma unroll
            for (int r = 0; r < 4; r++) {
                int m = m0 + wrow + fm * 16 + fq * 4 + r;
                int n = n0 + wcol + fn * 16 + frow;
                float v = acc[fm][fn][r];
                int b = m >> 10, t = m & 1023;
                int sect = n >> 11, nn = n & 2047;
                int h = nn >> 7, d = nn & 127;
                size_t bh = (size_t)(b * 16 + h);
                if (sect == 0)
                    qout[(bh * 1024 + t) * 128 + d] = f2bf(v * 0.08838834764831843f);
                else if (sect == 1)
                    kout[(bh * 2048 + 1024 + t) * 128 + d] = v;
                else
                    vout[(bh * 2048 + 1024 + t) * 128 + d] = v;
            }
        }
    }
}

// ---------------- out-proj GEMM: C[m,n] = sum_k A[m,k]*B[n,k], K=2048 ----------------
// 64x128 tile, 4 waves (each 64x32), BK=64, XOR-swizzled LDS (24 KB -> 6 blocks/CU).
// Kept: 512 blocks = 2/CU resident; 8-phase grid would be 64 blocks (25% fill).
__global__ __launch_bounds__(256) void gemm_out_kernel(
    const u16* __restrict__ A, const u16* __restrict__ Bm, float* __restrict__ cout) {
    __shared__ u16 As[64 * 64];     // 8 KB
    __shared__ u16 Bs[128 * 64];    // 16 KB
    const int tid = threadIdx.x;
    const int lane = tid & 63, wv = tid >> 6;
    const int wn = wv * 32;
    const int m0 = blockIdx.y * 64, n0 = blockIdx.x * 128;
    const int frow = lane & 15, fq = lane >> 4;
    const int swz = frow & 7;

    f32x4 acc[4][2];
#pragma unroll
    for (int a = 0; a < 4; a++)
#pragma unroll
        for (int b = 0; b < 2; b++) acc[a][b] = (f32x4){0.f, 0.f, 0.f, 0.f};

    for (int k0 = 0; k0 < 2048; k0 += 64) {
        __syncthreads();
#pragma unroll
        for (int i = 0; i < 2; i++) {
            int L = i * 256 + tid;             // A chunk 0..511
            int row = L >> 3;
            int c = (L & 7) ^ (row & 7);
            gld16(A + (size_t)(m0 + row) * 2048 + k0 + c * 8, As + i * 2048 + wv * 512);
        }
#pragma unroll
        for (int i = 0; i < 4; i++) {
            int L = i * 256 + tid;             // B chunk 0..1023
            int row = L >> 3;
            int c = (L & 7) ^ (row & 7);
            gld16(Bm + (size_t)(n0 + row) * 2048 + k0 + c * 8, Bs + i * 2048 + wv * 512);
        }
        __syncthreads();
#pragma unroll
        for (int kk = 0; kk < 2; kk++) {
            bf16x8 aF[4], bF[2];
#pragma unroll
            for (int f = 0; f < 4; f++)
                aF[f] = *(const bf16x8*)(As + (f * 16 + frow) * 64 + ((kk * 4 + fq) ^ swz) * 8);
#pragma unroll
            for (int f = 0; f < 2; f++)
                bF[f] = *(const bf16x8*)(Bs + (wn + f * 16 + frow) * 64 + ((kk * 4 + fq) ^ swz) * 8);
#pragma unroll
            for (int fm = 0; fm < 4; fm++)
#pragma unroll
                for (int fn = 0; fn < 2; fn++)
                    acc[fm][fn] = __builtin_amdgcn_mfma_f32_16x16x32_bf16(aF[fm], bF[fn], acc[fm][fn], 0, 0, 0);
        }
    }

#pragma unroll
    for (int fm = 0; fm < 4; fm++) {
#pragma unroll
        for (int fn = 0; fn < 2; fn++) {
#pragma unroll
            for (int r = 0; r < 4; r++) {
                int m = m0 + fm * 16 + fq * 4 + r;
                int n = n0 + wn + fn * 16 + frow;
                cout[(size_t)m * 2048 + n] = acc[fm][fn][r];
            }
        }
    }
}

// ---------------- flash attention, s-split for load balance ----------------
// 768 blocks, heavy-first:
//  bid<512: partial chunks of qi in [8,15]: qi = 15-(bid>>6), bh=(bid&63)>>1, c=bid&1.
//           chunk0 = tiles [0,ceil(n/2)), chunk1 = rest (incl. diagonal). Writes raw
//           m/l/O partials to workspace (overlaid on dead Wqkv region).
//  bid>=512: full blocks qi in [0,7] (loads 1..8), qi = 7-((bid-512)>>5), bh=(bid-512)&31.
// All block loads in [1..8.5] tiles; 768 blocks on 512 slots -> LPT-style balance.
__global__ __launch_bounds__(256) void attn_kernel(
    const u16* __restrict__ Qb, const u16* __restrict__ Kcb,
    const u16* __restrict__ Vtb, u16* __restrict__ AOb,
    float* __restrict__ PO, float* __restrict__ PML) {
    __shared__ u16 Qs[64 * 128];   // [t_local][d]  swizzled
    __shared__ u16 Ks[64 * 128];   // [s_local][d]  swizzled
    __shared__ u16 Vs[128 * 64];   // [d][s_local]  swizzled
    __shared__ u16 Ps[64 * 64];    // [t_local][s_local] swizzled
    const int bid = blockIdx.x;
    int bh, qi, st_begin, st_end, cidx;
    bool partial;
    if (bid < 512) {
        qi = 15 - (bid >> 6);
        int j = bid & 63;
        bh = j >> 1;
        int c = j & 1;
        int n = qi + 1, h0 = (n + 1) >> 1;
        st_begin = c ? h0 : 0;
        st_end = c ? n : h0;
        partial = true;
        cidx = c * 256 + bh * 8 + (qi - 8);
    } else {
        int j = bid - 512;
        qi = 7 - (j >> 5);
        bh = j & 31;
        st_begin = 0; st_end = qi + 1;
        partial = false; cidx = 0;
    }
    const int t0 = qi * 64;
    const int tid = threadIdx.x, lane = tid & 63, wv = tid >> 6;
    const int row_w = wv * 16;
    const int frow = lane & 15, fq = lane >> 4;
    const int swz = frow & 7;

    // stage Q (64x128 = 1024 chunks)
    const u16* Qg = Qb + ((size_t)bh * 1024 + t0) * 128;
#pragma unroll
    for (int i = 0; i < 4; i++) {
        int L = i * 256 + tid;
        int row = L >> 4;
        int c = (L & 15) ^ (row & 7);
        gld16(Qg + row * 128 + c * 8, Qs + i * 2048 + wv * 512);
    }

    float mrow[4], lrow[4];
    f32x4 Oacc[8];
#pragma unroll
    for (int r = 0; r < 4; r++) { mrow[r] = -1e30f; lrow[r] = 0.f; }
#pragma unroll
    for (int fd = 0; fd < 8; fd++) Oacc[fd] = (f32x4){0.f, 0.f, 0.f, 0.f};

    for (int st = st_begin; st < st_end; st++) {
        int s0 = st * 64;
        __syncthreads();
        const u16* Kg = Kcb + ((size_t)bh * 1024 + s0) * 128;
#pragma unroll
        for (int i = 0; i < 4; i++) {
            int L = i * 256 + tid;
            int row = L >> 4;
            int c = (L & 15) ^ (row & 7);
            gld16(Kg + row * 128 + c * 8, Ks + i * 2048 + wv * 512);
        }
        const u16* Vg = Vtb + (size_t)bh * 131072 + s0;
#pragma unroll
        for (int i = 0; i < 4; i++) {
            int L = i * 256 + tid;
            int row = L >> 3;
            int c = (L & 7) ^ (row & 7);
            gld16(Vg + row * 1024 + c * 8, Vs + i * 2048 + wv * 512);
        }
        __syncthreads();

        // S = Q K^T  (Q pre-scaled by 1/sqrt(dk))
        f32x4 S[4];
#pragma unroll
        for (int fn = 0; fn < 4; fn++) S[fn] = (f32x4){0.f, 0.f, 0.f, 0.f};
#pragma unroll
        for (int kk = 0; kk < 4; kk++) {
            bf16x8 aF = *(const bf16x8*)(Qs + (row_w + frow) * 128 + ((kk * 4 + fq) ^ swz) * 8);
#pragma unroll
            for (int fn = 0; fn < 4; fn++) {
                bf16x8 bF = *(const bf16x8*)(Ks + (fn * 16 + frow) * 128 + ((kk * 4 + fq) ^ swz) * 8);
                S[fn] = __builtin_amdgcn_mfma_f32_16x16x32_bf16(aF, bF, S[fn], 0, 0, 0);
            }
        }

        if (st == qi) {   // diagonal tile: mask s > t
#pragma unroll
            for (int fn = 0; fn < 4; fn++)
#pragma unroll
                for (int r = 0; r < 4; r++) {
                    int t = t0 + row_w + fq * 4 + r;
                    int s = s0 + fn * 16 + frow;
                    if (s > t) S[fn][r] = -1e30f;
                }
        }

        // online softmax per row
#pragma unroll
        for (int r = 0; r < 4; r++) {
            float mx = fmaxf(fmaxf(S[0][r], S[1][r]), fmaxf(S[2][r], S[3][r]));
            mx = fmaxf(mx, __shfl_xor(mx, 1));
            mx = fmaxf(mx, __shfl_xor(mx, 2));
            mx = fmaxf(mx, __shfl_xor(mx, 4));
            mx = fmaxf(mx, __shfl_xor(mx, 8));
            float mnew = fmaxf(mrow[r], mx);
            float alpha = __expf(mrow[r] - mnew);
            float rs = 0.f;
#pragma unroll
            for (int fn = 0; fn < 4; fn++) {
                float p = __expf(S[fn][r] - mnew);
                S[fn][r] = p;
                rs += p;
            }
            rs += __shfl_xor(rs, 1);
            rs += __shfl_xor(rs, 2);
            rs += __shfl_xor(rs, 4);
            rs += __shfl_xor(rs, 8);
            mrow[r] = mnew;
            lrow[r] = lrow[r] * alpha + rs;
#pragma unroll
            for (int fd = 0; fd < 8; fd++) Oacc[fd][r] *= alpha;
        }

        // P -> LDS (C-layout -> A-layout), per-wave region, swizzled; no barrier needed
#pragma unroll
        for (int fn = 0; fn < 4; fn++)
#pragma unroll
            for (int r = 0; r < 4; r++) {
                int pr = row_w + fq * 4 + r;
                int c = fn * 2 + (frow >> 3);
                Ps[pr * 64 + ((c ^ (pr & 7)) * 8) + (frow & 7)] = f2bf(S[fn][r]);
            }

        // O += P V
#pragma unroll
        for (int ks = 0; ks < 2; ks++) {
            int rr = row_w + frow;
            bf16x8 aP = *(const bf16x8*)(Ps + rr * 64 + ((ks * 4 + fq) ^ (rr & 7)) * 8);
#pragma unroll
            for (int fd = 0; fd < 8; fd++) {
                int vr = fd * 16 + frow;
                bf16x8 bV = *(const bf16x8*)(Vs + vr * 64 + ((ks * 4 + fq) ^ (vr & 7)) * 8);
                Oacc[fd] = __builtin_amdgcn_mfma_f32_16x16x32_bf16(aP, bV, Oacc[fd], 0, 0, 0);
            }
        }
    }

    if (partial) {
        // raw partial: O (un-normalized), m, l
        float* Od = PO + (size_t)cidx * 8192;
#pragma unroll
        for (int r = 0; r < 4; r++) {
            int row = row_w + fq * 4 + r;
#pragma unroll
            for (int fd = 0; fd < 8; fd++)
                Od[row * 128 + fd * 16 + frow] = Oacc[fd][r];
        }
        if (frow == 0) {
#pragma unroll
            for (int r = 0; r < 4; r++) {
                int row = row_w + fq * 4 + r;
                PML[cidx * 128 + row * 2] = mrow[r];
                PML[cidx * 128 + row * 2 + 1] = lrow[r];
            }
        }
    } else {
        // final: merge heads -> AOb [b*1024+t, h*128+d] bf16
        const int b = bh >> 4, h = bh & 15;
#pragma unroll
        for (int r = 0; r < 4; r++) {
            float rl = 1.0f / lrow[r];
            int t = t0 + row_w + fq * 4 + r;
#pragma unroll
            for (int fd = 0; fd < 8; fd++) {
                int col = h * 128 + fd * 16 + frow;
                AOb[((size_t)b * 1024 + t) * 2048 + col] = f2bf(Oacc[fd][r] * rl);
            }
        }
    }
}

// ---------------- merge the two s-chunks for qi >= 8 ----------------
__global__ __launch_bounds__(256) void attn_merge_kernel(
    const float* __restrict__ PO, const float* __restrict__ PML, u16* __restrict__ AOb) {
    const int idx = blockIdx.x;                // 0..255
    const int bh = idx >> 3, qi = 8 + (idx & 7);
    const int t0 = qi * 64;
    const int b = bh >> 4, h = bh & 15;
    const int tid = threadIdx.x;
    const int row = tid >> 2, cg = tid & 3;    // 64 rows x 4 col-groups of 32
    const float* O0 = PO + (size_t)idx * 8192;
    const float* O1 = PO + (size_t)(256 + idx) * 8192;
    float m0 = PML[idx * 128 + row * 2],        l0 = PML[idx * 128 + row * 2 + 1];
    float m1 = PML[(256 + idx) * 128 + row * 2], l1 = PML[(256 + idx) * 128 + row * 2 + 1];
    float mm = fmaxf(m0, m1);
    float w0 = __expf(m0 - mm), w1 = __expf(m1 - mm);
    float inv = 1.0f / (l0 * w0 + l1 * w1);
    u16* dst = AOb + ((size_t)b * 1024 + t0 + row) * 2048 + h * 128 + cg * 32;
#pragma unroll
    for (int j = 0; j < 8; j++) {
        f32x4 a = *(const f32x4*)(O0 + row * 128 + cg * 32 + j * 4);
        f32x4 c = *(const f32x4*)(O1 + row * 128 + cg * 32 + j * 4);
        u16x4 o = { f2bf((a.x * w0 + c.x * w1) * inv), f2bf((a.y * w0 + c.y * w1) * inv),
                    f2bf((a.z * w0 + c.z * w1) * inv), f2bf((a.w * w0 + c.w * w1) * inv) };
        *(u16x4*)(dst + j * 4) = o;
    }
}

extern "C" void kernel_launch(void* const* d_in, const int* in_sizes, int n_in,
                              void* d_out, int out_size, void* d_ws, size_t ws_size,
                              hipStream_t stream) {
    const float* x  = (const float*)d_in[0];
    const float* ck = (const float*)d_in[1];
    const float* cv = (const float*)d_in[2];
    const float* Wq = (const float*)d_in[3];
    const float* Wk = (const float*)d_in[4];
    const float* Wv = (const float*)d_in[5];
    const float* Wo = (const float*)d_in[6];

    float* out  = (float*)d_out;               // [2048, 2048]
    float* Kout = out + 4194304;               // [B,H,2048,128]
    float* Vout = out + 12582912;              // [B,H,2048,128]

    u16* xb   = (u16*)d_ws;                    // [2048,2048]
    u16* Wqkv = xb + 4194304;                  // [6144,2048] (dead after gemm0)
    u16* Wob  = Wqkv + 12582912;               // [2048,2048]
    u16* Qb   = Wob + 4194304;                 // [B,H,1024,128] (pre-scaled)
    u16* Kcb  = Qb + 4194304;                  // [B,H,1024,128]
    u16* Vtb  = Kcb + 4194304;                 // [B,H,128,1024]
    u16* AOb  = Vtb + 4194304;                 // [2048,2048]
    // attention partials overlaid on dead Wqkv region (25.1 MB; we use 17 MB)
    float* PO  = (float*)Wqkv;                 // 2*256*8192 floats
    float* PML = PO + 4194304;                 // 2*256*128 floats

    convall_kernel<<<4096, 256, 0, stream>>>(x, Wq, Wk, Wv, Wo, xb, Wqkv, Wob);
    cachek_kernel<<<1024, 256, 0, stream>>>(ck, Kout, Kcb);
    vtrans_kernel<<<dim3(32, 16, 2), 256, 0, stream>>>(cv, Vout, Vtb);

    gemm_qkv_kernel<<<dim3(32, 8), 512, 0, stream>>>(xb, Wqkv, Qb, Kout, Vout);
    attn_kernel<<<768, 256, 0, stream>>>(Qb, Kcb, Vtb, AOb, PO, PML);
    attn_merge_kernel<<<256, 256, 0, stream>>>(PO, PML, AOb);
    gemm_out_kernel<<<dim3(16, 32), 256, 0, stream>>>(AOb, Wob, out);
}